// Round 1
// baseline (1921.098 us; speedup 1.0000x reference)
//
#include <hip/hip_runtime.h>
#include <hip/hip_bf16.h>
#include <math.h>

#define BATCH   8
#define SEQLEN  4096
#define DMODEL  256
#define DSTATE  16
#define NHEADS  32
#define HEADDIM 16
#define DINNER  512
#define CONVDIM 544
#define DINPROJ 1088
#define NROWS   (BATCH*SEQLEN)

typedef __attribute__((ext_vector_type(8))) short short8;
typedef __attribute__((ext_vector_type(8))) unsigned short ushort8;
typedef __attribute__((ext_vector_type(4))) float f32x4;

__device__ __forceinline__ float bfu2f(unsigned short u){
  union { float f; unsigned int i; } x; x.i = ((unsigned int)u) << 16; return x.f;
}
__device__ __forceinline__ unsigned short f2bfu(float f){
  union { float f; unsigned int u; } v; v.f = f;
  v.u += 0x7fffu + ((v.u >> 16) & 1u);
  return (unsigned short)(v.u >> 16);
}

// ---------------- prep: cast u to bf16 ----------------
__global__ __launch_bounds__(256) void k_cast_u(const float* __restrict__ u, unsigned short* __restrict__ ub){
  int i = blockIdx.x*256 + threadIdx.x;
  float4 v = reinterpret_cast<const float4*>(u)[i];
  ushort4 o; o.x=f2bfu(v.x); o.y=f2bfu(v.y); o.z=f2bfu(v.z); o.w=f2bfu(v.w);
  reinterpret_cast<ushort4*>(ub)[i] = o;
}

// ---------------- prep: transpose+cast W (KxN -> NxK bf16) ----------------
__global__ __launch_bounds__(256) void k_transpose_cast(const float* __restrict__ W, unsigned short* __restrict__ WT, int K, int N){
  int idx = blockIdx.x*256 + threadIdx.x;
  if (idx >= N*K) return;
  int n = idx / K, k = idx - n*K;
  WT[idx] = f2bfu(W[(size_t)k*N + n]);
}

// ---------------- bf16 MFMA GEMM: C = A(MxK) * BT(NxK)^T ----------------
// BM=128, BN=64, BK=32; 4 waves (2x2), each wave 64x32 (4x2 fragments)
template<int EPI>
__global__ __launch_bounds__(256) void k_gemm(
    const unsigned short* __restrict__ A,
    const unsigned short* __restrict__ BT,
    int M, int N, int K,
    unsigned short* __restrict__ oz,
    unsigned short* __restrict__ oxbc,
    float* __restrict__ odtraw,
    float* __restrict__ of32)
{
  __shared__ uint4 lds[768];   // As: [0,512) = 128 rows x 4 slots ; Bs: [512,768) = 64 rows x 4 slots
  const int tid = threadIdx.x;
  const int lane = tid & 63;
  const int wid = tid >> 6;
  const int wr = wid >> 1, wc = wid & 1;
  const int bm0 = blockIdx.x * 128;
  const int bn0 = blockIdx.y * 64;
  const int fr = lane & 15, kq = lane >> 4;
  f32x4 acc[4][2] = {};
  const int nK = K >> 5;
  for (int kt = 0; kt < nK; ++kt){
    const int k0 = kt << 5;
    #pragma unroll
    for (int i = 0; i < 2; ++i){
      int c = tid + i*256;
      int row = c >> 2, slot = c & 3;
      uint4 v = *reinterpret_cast<const uint4*>(A + (size_t)(bm0+row)*K + k0 + slot*8);
      lds[row*4 + (slot ^ (row & 3))] = v;
    }
    {
      int row = tid >> 2, slot = tid & 3;
      uint4 v = *reinterpret_cast<const uint4*>(BT + (size_t)(bn0+row)*K + k0 + slot*8);
      lds[512 + row*4 + (slot ^ (row & 3))] = v;
    }
    __syncthreads();
    short8 bfrag[2];
    #pragma unroll
    for (int nf = 0; nf < 2; ++nf){
      int rb = wc*32 + nf*16 + fr;
      bfrag[nf] = *reinterpret_cast<const short8*>(&lds[512 + rb*4 + (kq ^ (rb & 3))]);
    }
    #pragma unroll
    for (int mf = 0; mf < 4; ++mf){
      int ra = wr*64 + mf*16 + fr;
      short8 afrag = *reinterpret_cast<const short8*>(&lds[ra*4 + (kq ^ (ra & 3))]);
      #pragma unroll
      for (int nf = 0; nf < 2; ++nf)
        acc[mf][nf] = __builtin_amdgcn_mfma_f32_16x16x32_bf16(afrag, bfrag[nf], acc[mf][nf], 0, 0, 0);
    }
    __syncthreads();
  }
  #pragma unroll
  for (int mf = 0; mf < 4; ++mf){
    #pragma unroll
    for (int nf = 0; nf < 2; ++nf){
      #pragma unroll
      for (int r = 0; r < 4; ++r){
        int m = bm0 + wr*64 + mf*16 + kq*4 + r;
        int n = bn0 + wc*32 + nf*16 + fr;
        float v = acc[mf][nf][r];
        if (EPI == 1){
          if (n < DINNER)                 oz[(size_t)m*DINNER + n] = f2bfu(v);
          else if (n < DINNER + CONVDIM)  oxbc[(size_t)m*CONVDIM + (n - DINNER)] = f2bfu(v);
          else                            odtraw[(size_t)m*NHEADS + (n - DINNER - CONVDIM)] = v;
        } else {
          of32[(size_t)m*N + n] = v;
        }
      }
    }
  }
}

// ---------------- depthwise causal conv (k=4) + bias + SiLU ----------------
__global__ __launch_bounds__(256) void k_conv(const unsigned short* __restrict__ xbc,
                                              const float* __restrict__ cw,
                                              const float* __restrict__ cb,
                                              float* __restrict__ out){
  int row = blockIdx.x;                 // b*SEQLEN + t
  int t = row & (SEQLEN-1);
  const unsigned short* xr = xbc + (size_t)row*CONVDIM;
  float* orow = out + (size_t)row*CONVDIM;
  for (int c = threadIdx.x; c < CONVDIM; c += 256){
    float acc = cb[c];
    #pragma unroll
    for (int j = 0; j < 4; ++j){
      int d = j - 3;
      if (t + d >= 0)
        acc += cw[c*4+j] * bfu2f(xr[(long)d*CONVDIM + c]);
    }
    orow[c] = acc / (1.f + __expf(-acc));   // silu
  }
}

// ---------------- dt = softplus(dtraw + bias); dA = exp(-exp(A_log)*dt) ----------------
__global__ __launch_bounds__(256) void k_dtda(const float* __restrict__ dtraw,
                                              const float* __restrict__ dt_bias,
                                              const float* __restrict__ A_log,
                                              float* __restrict__ dt_o,
                                              float* __restrict__ dA_o){
  int i = blockIdx.x*256 + threadIdx.x;   // NROWS*NHEADS
  int h = i & (NHEADS-1);
  float x = dtraw[i] + dt_bias[h];
  float dt = (x > 20.f) ? x : log1pf(expf(x));
  dt_o[i] = dt;
  dA_o[i] = expf(-expf(A_log[h]) * dt);
}

// ---------------- selective scan: one wave per (b,h) ----------------
// lane l: p = l&15 (head dim), g = l>>4; lane owns h[p][4g..4g+3]
__global__ __launch_bounds__(64) void k_scan(
    const float* __restrict__ cv, const float* __restrict__ dta,
    const float* __restrict__ daa, const float* __restrict__ Dv,
    unsigned short* __restrict__ ybf)
{
  const int bh = blockIdx.x;
  const int b = bh >> 5, h = bh & 31;
  const int l = threadIdx.x;
  const int p = l & 15, g = l >> 4;
  const float* base = cv + (size_t)b * SEQLEN * CONVDIM;
  const float* dtp = dta + (size_t)b * SEQLEN * NHEADS + h;
  const float* dap = daa + (size_t)b * SEQLEN * NHEADS + h;
  unsigned short* yp = ybf + (size_t)b * SEQLEN * DINNER + h*HEADDIM + p;
  const float Dh = Dv[h];
  float h0=0.f,h1=0.f,h2=0.f,h3=0.f;
  constexpr int PF = 16;
  float4 Bb[PF], Cb[PF];
  float xb[PF], tb[PF], ab[PF];
  #pragma unroll
  for (int i = 0; i < PF; ++i){
    const float* row = base + (size_t)i * CONVDIM;
    xb[i] = row[h*HEADDIM + p];
    Bb[i] = *reinterpret_cast<const float4*>(row + DINNER + 4*g);
    Cb[i] = *reinterpret_cast<const float4*>(row + DINNER + DSTATE + 4*g);
    tb[i] = dtp[(size_t)i*NHEADS];
    ab[i] = dap[(size_t)i*NHEADS];
  }
  for (int t0 = 0; t0 < SEQLEN; t0 += PF){
    #pragma unroll
    for (int i = 0; i < PF; ++i){
      const int t = t0 + i;
      const float x = xb[i];
      const float4 B4 = Bb[i];
      const float4 C4 = Cb[i];
      const float dt = tb[i], da = ab[i];
      const int tnext = t + PF;
      if (tnext < SEQLEN){
        const float* row = base + (size_t)tnext * CONVDIM;
        xb[i] = row[h*HEADDIM + p];
        Bb[i] = *reinterpret_cast<const float4*>(row + DINNER + 4*g);
        Cb[i] = *reinterpret_cast<const float4*>(row + DINNER + DSTATE + 4*g);
        tb[i] = dtp[(size_t)tnext*NHEADS];
        ab[i] = dap[(size_t)tnext*NHEADS];
      }
      const float dx = dt * x;
      h0 = fmaf(da, h0, dx*B4.x);
      h1 = fmaf(da, h1, dx*B4.y);
      h2 = fmaf(da, h2, dx*B4.z);
      h3 = fmaf(da, h3, dx*B4.w);
      float yv = h0*C4.x + h1*C4.y + h2*C4.z + h3*C4.w;
      yv += __shfl_xor(yv, 16, 64);
      yv += __shfl_xor(yv, 32, 64);
      if (l < 16){
        yp[(size_t)t * DINNER] = f2bfu(yv + Dh * x);
      }
    }
  }
}

// ---------------- gate (silu(z)*y) + RMSNorm + cast bf16 (in-place over z) ----------------
__global__ __launch_bounds__(64) void k_gate(const unsigned short* __restrict__ ybf,
                                             unsigned short* __restrict__ zbf,
                                             const float* __restrict__ nw){
  int row = blockIdx.x; int l = threadIdx.x;
  size_t base = (size_t)row*DINNER + l*8;
  ushort8 yv = *reinterpret_cast<const ushort8*>(ybf + base);
  ushort8 zv = *reinterpret_cast<const ushort8*>(zbf + base);
  float tv[8]; float ss = 0.f;
  #pragma unroll
  for (int j = 0; j < 8; ++j){
    float yf = bfu2f(yv[j]);
    float zf = bfu2f(zv[j]);
    float s = zf / (1.f + __expf(-zf));
    float t = yf * s; tv[j] = t; ss += t*t;
  }
  #pragma unroll
  for (int m = 1; m <= 32; m <<= 1) ss += __shfl_xor(ss, m, 64);
  float scale = rsqrtf(ss * (1.f/DINNER) + 1e-5f);
  ushort8 o;
  #pragma unroll
  for (int j = 0; j < 8; ++j) o[j] = f2bfu(tv[j] * scale * nw[l*8+j]);
  *reinterpret_cast<ushort8*>(zbf + base) = o;
}

extern "C" void kernel_launch(void* const* d_in, const int* in_sizes, int n_in,
                              void* d_out, int out_size, void* d_ws, size_t ws_size,
                              hipStream_t stream)
{
  const float* u       = (const float*)d_in[0];
  const float* W_in    = (const float*)d_in[1];
  const float* conv_w  = (const float*)d_in[2];
  const float* conv_b  = (const float*)d_in[3];
  const float* dt_bias = (const float*)d_in[4];
  const float* A_log   = (const float*)d_in[5];
  const float* Dvec    = (const float*)d_in[6];
  const float* norm_w  = (const float*)d_in[7];
  const float* W_out   = (const float*)d_in[8];
  float* out = (float*)d_out;
  char* ws = (char*)d_ws;

  unsigned short* ubf   = (unsigned short*)(ws + 0);          // 16,777,216 B
  unsigned short* wintT = (unsigned short*)(ws + 16777216);   //    557,056 B
  unsigned short* woutT = (unsigned short*)(ws + 17334272);   //    262,144 B
  unsigned short* zbf   = (unsigned short*)(ws + 17596416);   // 33,554,432 B (becomes t after gate)
  unsigned short* xbcbf = (unsigned short*)(ws + 51150848);   // 35,651,584 B (reused as y after conv)
  float* dtraw          = (float*)(ws + 86802432);            //  4,194,304 B
  float* convo          = (float*)(ws + 90996736);            // 71,303,168 B
  float* dtq            = (float*)(ws + 162299904);           //  4,194,304 B
  float* daq            = (float*)(ws + 166494208);           //  4,194,304 B  (total 170,688,512 B)
  unsigned short* ybf   = xbcbf;

  k_cast_u<<<NROWS*DMODEL/1024, 256, 0, stream>>>(u, ubf);
  k_transpose_cast<<<(DINPROJ*DMODEL+255)/256, 256, 0, stream>>>(W_in, wintT, DMODEL, DINPROJ);
  k_transpose_cast<<<(DINNER*DMODEL+255)/256, 256, 0, stream>>>(W_out, woutT, DINNER, DMODEL);

  dim3 g1(NROWS/128, DINPROJ/64);
  k_gemm<1><<<g1, 256, 0, stream>>>(ubf, wintT, NROWS, DINPROJ, DMODEL, zbf, xbcbf, dtraw, nullptr);

  k_conv<<<NROWS, 256, 0, stream>>>(xbcbf, conv_w, conv_b, convo);
  k_dtda<<<NROWS*NHEADS/256, 256, 0, stream>>>(dtraw, dt_bias, A_log, dtq, daq);
  k_scan<<<BATCH*NHEADS, 64, 0, stream>>>(convo, dtq, daq, Dvec, ybf);
  k_gate<<<NROWS, 64, 0, stream>>>(ybf, zbf, norm_w);

  dim3 g2(NROWS/128, DMODEL/64);
  k_gemm<2><<<g2, 256, 0, stream>>>(zbf, woutT, NROWS, DMODEL, DINNER, nullptr, nullptr, nullptr, out);
}

// Round 3
// 431.613 us; speedup vs baseline: 4.4510x; 4.4510x over previous
//
#include <hip/hip_runtime.h>
#include <hip/hip_bf16.h>
#include <math.h>

#define BATCH   8
#define SEQLEN  4096
#define DMODEL  256
#define DSTATE  16
#define NHEADS  32
#define HEADDIM 16
#define DINNER  512
#define CONVDIM 544
#define DINPROJ 1088
#define NROWS   (BATCH*SEQLEN)
#define CHUNK   128
#define NCH     (SEQLEN/CHUNK)   // 32

typedef __attribute__((ext_vector_type(8))) short short8;
typedef __attribute__((ext_vector_type(8))) unsigned short ushort8;
typedef __attribute__((ext_vector_type(4))) float f32x4;

__device__ __forceinline__ float bfu2f(unsigned short u){
  union { float f; unsigned int i; } x; x.i = ((unsigned int)u) << 16; return x.f;
}
__device__ __forceinline__ unsigned short f2bfu(float f){
  union { float f; unsigned int u; } v; v.f = f;
  v.u += 0x7fffu + ((v.u >> 16) & 1u);
  return (unsigned short)(v.u >> 16);
}

// ---------------- prep: cast u to bf16 ----------------
__global__ __launch_bounds__(256) void k_cast_u(const float* __restrict__ u, unsigned short* __restrict__ ub){
  int i = blockIdx.x*256 + threadIdx.x;
  float4 v = reinterpret_cast<const float4*>(u)[i];
  ushort4 o; o.x=f2bfu(v.x); o.y=f2bfu(v.y); o.z=f2bfu(v.z); o.w=f2bfu(v.w);
  reinterpret_cast<ushort4*>(ub)[i] = o;
}

// ---------------- prep: transpose+cast W (KxN -> NxK bf16) ----------------
__global__ __launch_bounds__(256) void k_transpose_cast(const float* __restrict__ W, unsigned short* __restrict__ WT, int K, int N){
  int idx = blockIdx.x*256 + threadIdx.x;
  if (idx >= N*K) return;
  int n = idx / K, k = idx - n*K;
  WT[idx] = f2bfu(W[(size_t)k*N + n]);
}

// ---------------- bf16 MFMA GEMM: C = A(MxK) * BT(NxK)^T ----------------
// BM=128, BN=64, BK=32; 4 waves (2x2), each wave 64x32 (4x2 fragments)
template<int EPI>
__global__ __launch_bounds__(256) void k_gemm(
    const unsigned short* __restrict__ A,
    const unsigned short* __restrict__ BT,
    int M, int N, int K,
    unsigned short* __restrict__ oz,
    unsigned short* __restrict__ oxbc,
    float* __restrict__ odtraw,
    float* __restrict__ of32)
{
  __shared__ uint4 lds[768];   // As: [0,512) = 128 rows x 4 slots ; Bs: [512,768) = 64 rows x 4 slots
  const int tid = threadIdx.x;
  const int lane = tid & 63;
  const int wid = tid >> 6;
  const int wr = wid >> 1, wc = wid & 1;
  const int bm0 = blockIdx.x * 128;
  const int bn0 = blockIdx.y * 64;
  const int fr = lane & 15, kq = lane >> 4;
  f32x4 acc[4][2] = {};
  const int nK = K >> 5;
  for (int kt = 0; kt < nK; ++kt){
    const int k0 = kt << 5;
    #pragma unroll
    for (int i = 0; i < 2; ++i){
      int c = tid + i*256;
      int row = c >> 2, slot = c & 3;
      uint4 v = *reinterpret_cast<const uint4*>(A + (size_t)(bm0+row)*K + k0 + slot*8);
      lds[row*4 + (slot ^ (row & 3))] = v;
    }
    {
      int row = tid >> 2, slot = tid & 3;
      uint4 v = *reinterpret_cast<const uint4*>(BT + (size_t)(bn0+row)*K + k0 + slot*8);
      lds[512 + row*4 + (slot ^ (row & 3))] = v;
    }
    __syncthreads();
    short8 bfrag[2];
    #pragma unroll
    for (int nf = 0; nf < 2; ++nf){
      int rb = wc*32 + nf*16 + fr;
      bfrag[nf] = *reinterpret_cast<const short8*>(&lds[512 + rb*4 + (kq ^ (rb & 3))]);
    }
    #pragma unroll
    for (int mf = 0; mf < 4; ++mf){
      int ra = wr*64 + mf*16 + fr;
      short8 afrag = *reinterpret_cast<const short8*>(&lds[ra*4 + (kq ^ (ra & 3))]);
      #pragma unroll
      for (int nf = 0; nf < 2; ++nf)
        acc[mf][nf] = __builtin_amdgcn_mfma_f32_16x16x32_bf16(afrag, bfrag[nf], acc[mf][nf], 0, 0, 0);
    }
    __syncthreads();
  }
  #pragma unroll
  for (int mf = 0; mf < 4; ++mf){
    #pragma unroll
    for (int nf = 0; nf < 2; ++nf){
      #pragma unroll
      for (int r = 0; r < 4; ++r){
        int m = bm0 + wr*64 + mf*16 + kq*4 + r;
        int n = bn0 + wc*32 + nf*16 + fr;
        float v = acc[mf][nf][r];
        if (EPI == 1){
          if (n < DINNER)                 oz[(size_t)m*DINNER + n] = f2bfu(v);
          else if (n < DINNER + CONVDIM)  oxbc[(size_t)m*CONVDIM + (n - DINNER)] = f2bfu(v);
          else                            odtraw[(size_t)m*NHEADS + (n - DINNER - CONVDIM)] = v;
        } else {
          of32[(size_t)m*N + n] = v;
        }
      }
    }
  }
}

// ---------------- depthwise causal conv (k=4) + bias + SiLU ----------------
__global__ __launch_bounds__(256) void k_conv(const unsigned short* __restrict__ xbc,
                                              const float* __restrict__ cw,
                                              const float* __restrict__ cb,
                                              float* __restrict__ out){
  int row = blockIdx.x;                 // b*SEQLEN + t
  int t = row & (SEQLEN-1);
  const unsigned short* xr = xbc + (size_t)row*CONVDIM;
  float* orow = out + (size_t)row*CONVDIM;
  for (int c = threadIdx.x; c < CONVDIM; c += 256){
    float acc = cb[c];
    #pragma unroll
    for (int j = 0; j < 4; ++j){
      int d = j - 3;
      if (t + d >= 0)
        acc += cw[c*4+j] * bfu2f(xr[(long)d*CONVDIM + c]);
    }
    orow[c] = acc / (1.f + __expf(-acc));   // silu
  }
}

// ---------------- dt = softplus(dtraw + bias); dA = exp(-exp(A_log)*dt) ----------------
__global__ __launch_bounds__(256) void k_dtda(const float* __restrict__ dtraw,
                                              const float* __restrict__ dt_bias,
                                              const float* __restrict__ A_log,
                                              float* __restrict__ dt_o,
                                              float* __restrict__ dA_o){
  int i = blockIdx.x*256 + threadIdx.x;   // NROWS*NHEADS
  int h = i & (NHEADS-1);
  float x = dtraw[i] + dt_bias[h];
  float dt = (x > 20.f) ? x : log1pf(expf(x));
  dt_o[i] = dt;
  dA_o[i] = expf(-expf(A_log[h]) * dt);
}

// ======== chunked selective scan ========
// pass 1: per-(b,h,chunk) local scan (h0=0). Writes y_local (+D*x) OVER the
// x-slot of convo (f32), final state H_c to st, decay product P_c to Pp.
__global__ __launch_bounds__(256) void k_scan1(
    float* __restrict__ cv, const float* __restrict__ dta,
    const float* __restrict__ daa, const float* __restrict__ Dv,
    float* __restrict__ st, float* __restrict__ Pp)
{
  const int gi = blockIdx.x*4 + (threadIdx.x >> 6);   // global chunk index
  const int l = threadIdx.x & 63;
  const int bh = gi >> 5;          // NCH = 32
  const int c  = gi & (NCH-1);
  const int b = bh >> 5, h = bh & 31;
  const int p = l & 15, g = l >> 4;
  const size_t row0 = (size_t)b*SEQLEN + (size_t)c*CHUNK;
  float* base = cv + row0*CONVDIM;
  const float* dtp = dta + row0*NHEADS + h;
  const float* dap = daa + row0*NHEADS + h;
  const float Dh = Dv[h];
  float h0=0.f,h1=0.f,h2=0.f,h3=0.f, cum=1.f;
  constexpr int PF = 4;
  float4 Bb[PF], Cb[PF]; float xb[PF], tb[PF], ab[PF];
  #pragma unroll
  for (int i = 0; i < PF; ++i){
    const float* row = base + (size_t)i*CONVDIM;
    xb[i] = row[h*HEADDIM + p];
    Bb[i] = *reinterpret_cast<const float4*>(row + DINNER + 4*g);
    Cb[i] = *reinterpret_cast<const float4*>(row + DINNER + DSTATE + 4*g);
    tb[i] = dtp[(size_t)i*NHEADS];
    ab[i] = dap[(size_t)i*NHEADS];
  }
  for (int t0 = 0; t0 < CHUNK; t0 += PF){
    #pragma unroll
    for (int i = 0; i < PF; ++i){
      const int t = t0 + i;
      const float x = xb[i];
      const float4 B4 = Bb[i], C4 = Cb[i];
      const float dt = tb[i], da = ab[i];
      const int tn = t + PF;
      if (tn < CHUNK){
        const float* row = base + (size_t)tn*CONVDIM;
        xb[i] = row[h*HEADDIM + p];
        Bb[i] = *reinterpret_cast<const float4*>(row + DINNER + 4*g);
        Cb[i] = *reinterpret_cast<const float4*>(row + DINNER + DSTATE + 4*g);
        tb[i] = dtp[(size_t)tn*NHEADS];
        ab[i] = dap[(size_t)tn*NHEADS];
      }
      const float dx = dt * x;
      h0 = fmaf(da, h0, dx*B4.x);
      h1 = fmaf(da, h1, dx*B4.y);
      h2 = fmaf(da, h2, dx*B4.z);
      h3 = fmaf(da, h3, dx*B4.w);
      cum *= da;
      float yv = h0*C4.x + h1*C4.y + h2*C4.z + h3*C4.w;
      yv += __shfl_xor(yv, 16, 64);
      yv += __shfl_xor(yv, 32, 64);
      if (l < 16)
        base[(size_t)t*CONVDIM + h*HEADDIM + p] = yv + Dh * x;   // y_local over x-slot
    }
  }
  *reinterpret_cast<float4*>(st + ((size_t)gi*64 + l)*4) = make_float4(h0,h1,h2,h3);
  if (l == 0) Pp[gi] = cum;
}

// pass 2: inter-chunk scan. st[c] := hinit_c (state before chunk c), in place.
__global__ __launch_bounds__(64) void k_scan2(float* __restrict__ st, const float* __restrict__ Pp){
  const int bh = blockIdx.x;
  const int l = threadIdx.x;
  float4 carry = make_float4(0.f,0.f,0.f,0.f);
  for (int c = 0; c < NCH; ++c){
    size_t idx = ((size_t)(bh*NCH + c)*64 + l)*4;
    float4 Hc = *reinterpret_cast<const float4*>(st + idx);
    float Pc = Pp[bh*NCH + c];
    *reinterpret_cast<float4*>(st + idx) = carry;
    carry.x = fmaf(Pc, carry.x, Hc.x);
    carry.y = fmaf(Pc, carry.y, Hc.y);
    carry.z = fmaf(Pc, carry.z, Hc.z);
    carry.w = fmaf(Pc, carry.w, Hc.w);
  }
}

// pass 3: y_t = y_local_t + cumda_t * (hinit . C_t), cast bf16.
__global__ __launch_bounds__(256) void k_scan3(
    const float* __restrict__ cv, const float* __restrict__ daa,
    const float* __restrict__ st, unsigned short* __restrict__ ybf)
{
  const int gi = blockIdx.x*4 + (threadIdx.x >> 6);
  const int l = threadIdx.x & 63;
  const int bh = gi >> 5;
  const int c  = gi & (NCH-1);
  const int b = bh >> 5, h = bh & 31;
  const int p = l & 15, g = l >> 4;
  const size_t row0 = (size_t)b*SEQLEN + (size_t)c*CHUNK;
  const float* base = cv + row0*CONVDIM;
  const float* dap = daa + row0*NHEADS + h;
  unsigned short* yp = ybf + row0*DINNER + h*HEADDIM + p;
  const float4 hi = *reinterpret_cast<const float4*>(st + ((size_t)gi*64 + l)*4);
  float cum = 1.f;
  constexpr int PF = 4;
  float4 Cb[PF]; float yb[PF], ab[PF];
  #pragma unroll
  for (int i = 0; i < PF; ++i){
    const float* row = base + (size_t)i*CONVDIM;
    yb[i] = row[h*HEADDIM + p];
    Cb[i] = *reinterpret_cast<const float4*>(row + DINNER + DSTATE + 4*g);
    ab[i] = dap[(size_t)i*NHEADS];
  }
  for (int t0 = 0; t0 < CHUNK; t0 += PF){
    #pragma unroll
    for (int i = 0; i < PF; ++i){
      const int t = t0 + i;
      const float yloc = yb[i];
      const float4 C4 = Cb[i];
      const float da = ab[i];
      const int tn = t + PF;
      if (tn < CHUNK){
        const float* row = base + (size_t)tn*CONVDIM;
        yb[i] = row[h*HEADDIM + p];
        Cb[i] = *reinterpret_cast<const float4*>(row + DINNER + DSTATE + 4*g);
        ab[i] = dap[(size_t)tn*NHEADS];
      }
      cum *= da;
      float corr = hi.x*C4.x + hi.y*C4.y + hi.z*C4.z + hi.w*C4.w;
      corr += __shfl_xor(corr, 16, 64);
      corr += __shfl_xor(corr, 32, 64);
      if (l < 16)
        yp[(size_t)t*DINNER] = f2bfu(yloc + cum * corr);
    }
  }
}

// ---------------- gate (silu(z)*y) + RMSNorm + cast bf16 (in-place over z) ----------------
__global__ __launch_bounds__(64) void k_gate(const unsigned short* __restrict__ ybf,
                                             unsigned short* __restrict__ zbf,
                                             const float* __restrict__ nw){
  int row = blockIdx.x; int l = threadIdx.x;
  size_t base = (size_t)row*DINNER + l*8;
  ushort8 yv = *reinterpret_cast<const ushort8*>(ybf + base);
  ushort8 zv = *reinterpret_cast<const ushort8*>(zbf + base);
  float tv[8]; float ss = 0.f;
  #pragma unroll
  for (int j = 0; j < 8; ++j){
    float yf = bfu2f(yv[j]);
    float zf = bfu2f(zv[j]);
    float s = zf / (1.f + __expf(-zf));
    float t = yf * s; tv[j] = t; ss += t*t;
  }
  #pragma unroll
  for (int m = 1; m <= 32; m <<= 1) ss += __shfl_xor(ss, m, 64);
  float scale = rsqrtf(ss * (1.f/DINNER) + 1e-5f);
  ushort8 o;
  #pragma unroll
  for (int j = 0; j < 8; ++j) o[j] = f2bfu(tv[j] * scale * nw[l*8+j]);
  *reinterpret_cast<ushort8*>(zbf + base) = o;
}

extern "C" void kernel_launch(void* const* d_in, const int* in_sizes, int n_in,
                              void* d_out, int out_size, void* d_ws, size_t ws_size,
                              hipStream_t stream)
{
  const float* u       = (const float*)d_in[0];
  const float* W_in    = (const float*)d_in[1];
  const float* conv_w  = (const float*)d_in[2];
  const float* conv_b  = (const float*)d_in[3];
  const float* dt_bias = (const float*)d_in[4];
  const float* A_log   = (const float*)d_in[5];
  const float* Dvec    = (const float*)d_in[6];
  const float* norm_w  = (const float*)d_in[7];
  const float* W_out   = (const float*)d_in[8];
  float* out = (float*)d_out;
  char* ws = (char*)d_ws;

  unsigned short* ubf   = (unsigned short*)(ws + 0);          // 16,777,216 B (dead after GEMM1)
  float* chst           = (float*)(ws + 0);                   //  8,388,608 B (pass1..3, overlaps ubf)
  float* Pp             = (float*)(ws + 8388608);             //     32,768 B (overlaps ubf)
  unsigned short* wintT = (unsigned short*)(ws + 16777216);   //    557,056 B
  unsigned short* woutT = (unsigned short*)(ws + 17334272);   //    262,144 B
  unsigned short* zbf   = (unsigned short*)(ws + 17596416);   // 33,554,432 B (becomes t after gate)
  unsigned short* xbcbf = (unsigned short*)(ws + 51150848);   // 35,651,584 B (reused as y bf16)
  float* dtraw          = (float*)(ws + 86802432);            //  4,194,304 B
  float* convo          = (float*)(ws + 90996736);            // 71,303,168 B (x-slot becomes y_local)
  float* dtq            = (float*)(ws + 162299904);           //  4,194,304 B
  float* daq            = (float*)(ws + 166494208);           //  4,194,304 B  (total 170,688,512 B)
  unsigned short* ybf   = xbcbf;

  k_cast_u<<<NROWS*DMODEL/1024, 256, 0, stream>>>(u, ubf);
  k_transpose_cast<<<(DINPROJ*DMODEL+255)/256, 256, 0, stream>>>(W_in, wintT, DMODEL, DINPROJ);
  k_transpose_cast<<<(DINNER*DMODEL+255)/256, 256, 0, stream>>>(W_out, woutT, DINNER, DMODEL);

  dim3 g1(NROWS/128, DINPROJ/64);
  k_gemm<1><<<g1, 256, 0, stream>>>(ubf, wintT, NROWS, DINPROJ, DMODEL, zbf, xbcbf, dtraw, nullptr);

  k_conv<<<NROWS, 256, 0, stream>>>(xbcbf, conv_w, conv_b, convo);
  k_dtda<<<NROWS*NHEADS/256, 256, 0, stream>>>(dtraw, dt_bias, A_log, dtq, daq);

  k_scan1<<<BATCH*NHEADS*NCH/4, 256, 0, stream>>>(convo, dtq, daq, Dvec, chst, Pp);
  k_scan2<<<BATCH*NHEADS, 64, 0, stream>>>(chst, Pp);
  k_scan3<<<BATCH*NHEADS*NCH/4, 256, 0, stream>>>(convo, daq, chst, ybf);

  k_gate<<<NROWS, 64, 0, stream>>>(ybf, zbf, norm_w);

  dim3 g2(NROWS/128, DMODEL/64);
  k_gemm<2><<<g2, 256, 0, stream>>>(zbf, woutT, NROWS, DMODEL, DINNER, nullptr, nullptr, nullptr, out);
}

// Round 4
// 289.234 us; speedup vs baseline: 6.6420x; 1.4923x over previous
//
#include <hip/hip_runtime.h>
#include <hip/hip_bf16.h>
#include <math.h>

#define BATCH   8
#define SEQLEN  4096
#define DMODEL  256
#define DSTATE  16
#define NHEADS  32
#define HEADDIM 16
#define DINNER  512
#define CONVDIM 544
#define DINPROJ 1088
#define NROWS   (BATCH*SEQLEN)
#define CHUNK   64
#define NCH     (SEQLEN/CHUNK)   // 64

typedef __attribute__((ext_vector_type(8))) short short8;
typedef __attribute__((ext_vector_type(8))) unsigned short ushort8;
typedef __attribute__((ext_vector_type(4))) float f32x4;

__device__ __forceinline__ float bfu2f(unsigned short u){
  union { float f; unsigned int i; } x; x.i = ((unsigned int)u) << 16; return x.f;
}
__device__ __forceinline__ unsigned short f2bfu(float f){
  union { float f; unsigned int u; } v; v.f = f;
  v.u += 0x7fffu + ((v.u >> 16) & 1u);
  return (unsigned short)(v.u >> 16);
}

// ---------------- prep: cast u to bf16 ----------------
__global__ __launch_bounds__(256) void k_cast_u(const float* __restrict__ u, unsigned short* __restrict__ ub){
  int i = blockIdx.x*256 + threadIdx.x;
  float4 v = reinterpret_cast<const float4*>(u)[i];
  ushort4 o; o.x=f2bfu(v.x); o.y=f2bfu(v.y); o.z=f2bfu(v.z); o.w=f2bfu(v.w);
  reinterpret_cast<ushort4*>(ub)[i] = o;
}

// ---------------- prep: transpose+cast W (KxN -> NxK bf16) ----------------
__global__ __launch_bounds__(256) void k_transpose_cast(const float* __restrict__ W, unsigned short* __restrict__ WT, int K, int N){
  int idx = blockIdx.x*256 + threadIdx.x;
  if (idx >= N*K) return;
  int n = idx / K, k = idx - n*K;
  WT[idx] = f2bfu(W[(size_t)k*N + n]);
}

// ---------------- bf16 MFMA GEMM: C = A(MxK) * BT(NxK)^T ----------------
template<int EPI>
__global__ __launch_bounds__(256) void k_gemm(
    const unsigned short* __restrict__ A,
    const unsigned short* __restrict__ BT,
    int M, int N, int K,
    unsigned short* __restrict__ oz,
    unsigned short* __restrict__ oxbc,
    float* __restrict__ odtraw,
    float* __restrict__ of32)
{
  __shared__ uint4 lds[768];
  const int tid = threadIdx.x;
  const int lane = tid & 63;
  const int wid = tid >> 6;
  const int wr = wid >> 1, wc = wid & 1;
  const int bm0 = blockIdx.x * 128;
  const int bn0 = blockIdx.y * 64;
  const int fr = lane & 15, kq = lane >> 4;
  f32x4 acc[4][2] = {};
  const int nK = K >> 5;
  for (int kt = 0; kt < nK; ++kt){
    const int k0 = kt << 5;
    #pragma unroll
    for (int i = 0; i < 2; ++i){
      int c = tid + i*256;
      int row = c >> 2, slot = c & 3;
      uint4 v = *reinterpret_cast<const uint4*>(A + (size_t)(bm0+row)*K + k0 + slot*8);
      lds[row*4 + (slot ^ (row & 3))] = v;
    }
    {
      int row = tid >> 2, slot = tid & 3;
      uint4 v = *reinterpret_cast<const uint4*>(BT + (size_t)(bn0+row)*K + k0 + slot*8);
      lds[512 + row*4 + (slot ^ (row & 3))] = v;
    }
    __syncthreads();
    short8 bfrag[2];
    #pragma unroll
    for (int nf = 0; nf < 2; ++nf){
      int rb = wc*32 + nf*16 + fr;
      bfrag[nf] = *reinterpret_cast<const short8*>(&lds[512 + rb*4 + (kq ^ (rb & 3))]);
    }
    #pragma unroll
    for (int mf = 0; mf < 4; ++mf){
      int ra = wr*64 + mf*16 + fr;
      short8 afrag = *reinterpret_cast<const short8*>(&lds[ra*4 + (kq ^ (ra & 3))]);
      #pragma unroll
      for (int nf = 0; nf < 2; ++nf)
        acc[mf][nf] = __builtin_amdgcn_mfma_f32_16x16x32_bf16(afrag, bfrag[nf], acc[mf][nf], 0, 0, 0);
    }
    __syncthreads();
  }
  #pragma unroll
  for (int mf = 0; mf < 4; ++mf){
    #pragma unroll
    for (int nf = 0; nf < 2; ++nf){
      #pragma unroll
      for (int r = 0; r < 4; ++r){
        int m = bm0 + wr*64 + mf*16 + kq*4 + r;
        int n = bn0 + wc*32 + nf*16 + fr;
        float v = acc[mf][nf][r];
        if (EPI == 1){
          if (n < DINNER)                 oz[(size_t)m*DINNER + n] = f2bfu(v);
          else if (n < DINNER + CONVDIM)  oxbc[(size_t)m*CONVDIM + (n - DINNER)] = f2bfu(v);
          else                            odtraw[(size_t)m*NHEADS + (n - DINNER - CONVDIM)] = v;
        } else {
          of32[(size_t)m*N + n] = v;
        }
      }
    }
  }
}

// ---------------- depthwise causal conv (k=4) + bias + SiLU ----------------
__global__ __launch_bounds__(256) void k_conv(const unsigned short* __restrict__ xbc,
                                              const float* __restrict__ cw,
                                              const float* __restrict__ cb,
                                              float* __restrict__ out){
  int row = blockIdx.x;                 // b*SEQLEN + t
  int t = row & (SEQLEN-1);
  const unsigned short* xr = xbc + (size_t)row*CONVDIM;
  float* orow = out + (size_t)row*CONVDIM;
  for (int c = threadIdx.x; c < CONVDIM; c += 256){
    float acc = cb[c];
    #pragma unroll
    for (int j = 0; j < 4; ++j){
      int d = j - 3;
      if (t + d >= 0)
        acc += cw[c*4+j] * bfu2f(xr[(long)d*CONVDIM + c]);
    }
    orow[c] = acc / (1.f + __expf(-acc));   // silu
  }
}

// ---------------- dt = softplus(dtraw + bias); dA = exp(-exp(A_log)*dt) ----------------
__global__ __launch_bounds__(256) void k_dtda(const float* __restrict__ dtraw,
                                              const float* __restrict__ dt_bias,
                                              const float* __restrict__ A_log,
                                              float* __restrict__ dt_o,
                                              float* __restrict__ dA_o){
  int i = blockIdx.x*256 + threadIdx.x;   // NROWS*NHEADS
  int h = i & (NHEADS-1);
  float x = dtraw[i] + dt_bias[h];
  float dt = (x > 20.f) ? x : log1pf(expf(x));
  dt_o[i] = dt;
  dA_o[i] = expf(-expf(A_log[h]) * dt);
}

// ======== chunked selective scan, 4 heads/wave, full-n per lane ========
// wave handles (b, quad q, chunk c); lane l = hh*16+p, head h = q*4+hh.
// Each lane holds state h[p][n], n=0..15 in registers. B/C loads are
// wave-uniform (shared across the 4 heads); x load / y store coalesced 256B.
// pass 1: local scan (h0=0); y_local(+D*x) written over x-slot of convo (f32);
// final state -> st, decay product -> Pp.
__global__ __launch_bounds__(256,4) void k_scan1(
    float* __restrict__ cv, const float* __restrict__ dta,
    const float* __restrict__ daa, const float* __restrict__ Dv,
    float* __restrict__ st, float* __restrict__ Pp)
{
  const int bid = blockIdx.x;
  const int qh = bid & 1;
  const int c  = (bid >> 1) & (NCH-1);
  const int b  = bid >> 7;
  const int w  = threadIdx.x >> 6;
  const int l  = threadIdx.x & 63;
  const int q  = qh*4 + w;
  const int hh = l >> 4, p = l & 15;
  const int h  = q*4 + hh;
  const size_t row0 = (size_t)b*SEQLEN + (size_t)c*CHUNK;
  float* base = cv + row0*CONVDIM;
  const float* dtp = dta + row0*NHEADS + h;
  const float* dap = daa + row0*NHEADS + h;
  const float Dh = Dv[h];
  const int xoff = q*64 + l;          // = h*HEADDIM + p
  float hs[16];
  #pragma unroll
  for (int n = 0; n < 16; ++n) hs[n] = 0.f;
  float cum = 1.f;
  float Ba[16], Ca[16], Bb[16], Cb[16];
  float xA, xB_, tA, tB, aA, aB;
  {
    const float* r = base;
    xA = r[xoff];
    #pragma unroll
    for (int k = 0; k < 4; ++k){
      *reinterpret_cast<float4*>(&Ba[4*k]) = *reinterpret_cast<const float4*>(r + DINNER + 4*k);
      *reinterpret_cast<float4*>(&Ca[4*k]) = *reinterpret_cast<const float4*>(r + DINNER + DSTATE + 4*k);
    }
    tA = dtp[0]; aA = dap[0];
  }
  for (int t = 0; t < CHUNK; t += 2){
    { // even step: compute set A, prefetch t+1 -> set B
      const float* r = base + (size_t)(t+1)*CONVDIM;
      xB_ = r[xoff];
      #pragma unroll
      for (int k = 0; k < 4; ++k){
        *reinterpret_cast<float4*>(&Bb[4*k]) = *reinterpret_cast<const float4*>(r + DINNER + 4*k);
        *reinterpret_cast<float4*>(&Cb[4*k]) = *reinterpret_cast<const float4*>(r + DINNER + DSTATE + 4*k);
      }
      tB = dtp[(size_t)(t+1)*NHEADS]; aB = dap[(size_t)(t+1)*NHEADS];
      const float dx = tA * xA;
      float y = 0.f;
      #pragma unroll
      for (int n = 0; n < 16; ++n) hs[n] = fmaf(aA, hs[n], dx*Ba[n]);
      #pragma unroll
      for (int n = 0; n < 16; ++n) y = fmaf(hs[n], Ca[n], y);
      cum *= aA;
      base[(size_t)t*CONVDIM + xoff] = y + Dh*xA;
    }
    { // odd step: compute set B, prefetch t+2 -> set A (last prefetch reads 1 row past chunk: harmless, inside ws)
      const float* r = base + (size_t)(t+2)*CONVDIM;
      xA = r[xoff];
      #pragma unroll
      for (int k = 0; k < 4; ++k){
        *reinterpret_cast<float4*>(&Ba[4*k]) = *reinterpret_cast<const float4*>(r + DINNER + 4*k);
        *reinterpret_cast<float4*>(&Ca[4*k]) = *reinterpret_cast<const float4*>(r + DINNER + DSTATE + 4*k);
      }
      tA = dtp[(size_t)(t+2)*NHEADS]; aA = dap[(size_t)(t+2)*NHEADS];
      const float dx = tB * xB_;
      float y = 0.f;
      #pragma unroll
      for (int n = 0; n < 16; ++n) hs[n] = fmaf(aB, hs[n], dx*Bb[n]);
      #pragma unroll
      for (int n = 0; n < 16; ++n) y = fmaf(hs[n], Cb[n], y);
      cum *= aB;
      base[(size_t)(t+1)*CONVDIM + xoff] = y + Dh*xB_;
    }
  }
  float* sp = st + (((size_t)(b*NHEADS + h)*NCH + c)*16 + p)*16;
  #pragma unroll
  for (int k = 0; k < 4; ++k)
    *reinterpret_cast<float4*>(sp + 4*k) = *reinterpret_cast<const float4*>(&hs[4*k]);
  if (p == 0) Pp[((size_t)b*NHEADS + h)*NCH + c] = cum;
}

// pass 2: inter-chunk scan; st[c] := hinit_c in place. lane l owns (p=l>>2, n=4*(l&3)..)
__global__ __launch_bounds__(64) void k_scan2(float* __restrict__ st, const float* __restrict__ Pp){
  const int bh = blockIdx.x;
  const int l = threadIdx.x;
  float* sb = st + (size_t)bh*NCH*256 + l*4;
  const float* pb = Pp + (size_t)bh*NCH;
  float4 carry = make_float4(0.f,0.f,0.f,0.f);
  float4 Hb[4]; float Pb[4];
  #pragma unroll
  for (int i = 0; i < 4; ++i){
    Hb[i] = *reinterpret_cast<const float4*>(sb + (size_t)i*256);
    Pb[i] = pb[i];
  }
  for (int c0 = 0; c0 < NCH; c0 += 4){
    #pragma unroll
    for (int i = 0; i < 4; ++i){
      const int cc = c0 + i;
      float4 Hc = Hb[i]; float Pc = Pb[i];
      if (cc + 4 < NCH){
        Hb[i] = *reinterpret_cast<const float4*>(sb + (size_t)(cc+4)*256);
        Pb[i] = pb[cc+4];
      }
      *reinterpret_cast<float4*>(sb + (size_t)cc*256) = carry;
      carry.x = fmaf(Pc, carry.x, Hc.x);
      carry.y = fmaf(Pc, carry.y, Hc.y);
      carry.z = fmaf(Pc, carry.z, Hc.z);
      carry.w = fmaf(Pc, carry.w, Hc.w);
    }
  }
}

// pass 3: y_t = y_local_t + cum_t * (hinit . C_t), cast bf16. Same layout as pass 1.
__global__ __launch_bounds__(256,4) void k_scan3(
    const float* __restrict__ cv, const float* __restrict__ daa,
    const float* __restrict__ st, unsigned short* __restrict__ ybf)
{
  const int bid = blockIdx.x;
  const int qh = bid & 1;
  const int c  = (bid >> 1) & (NCH-1);
  const int b  = bid >> 7;
  const int w  = threadIdx.x >> 6;
  const int l  = threadIdx.x & 63;
  const int q  = qh*4 + w;
  const int hh = l >> 4, p = l & 15;
  const int h  = q*4 + hh;
  const size_t row0 = (size_t)b*SEQLEN + (size_t)c*CHUNK;
  const float* base = cv + row0*CONVDIM;
  const float* dap = daa + row0*NHEADS + h;
  unsigned short* yp = ybf + row0*DINNER + q*64 + l;
  const int xoff = q*64 + l;
  float hi[16];
  {
    const float* sp = st + (((size_t)(b*NHEADS + h)*NCH + c)*16 + p)*16;
    #pragma unroll
    for (int k = 0; k < 4; ++k)
      *reinterpret_cast<float4*>(&hi[4*k]) = *reinterpret_cast<const float4*>(sp + 4*k);
  }
  float cum = 1.f;
  float Ca[16], Cb[16];
  float ylA, ylB, aA, aB;
  {
    const float* r = base;
    ylA = r[xoff];
    #pragma unroll
    for (int k = 0; k < 4; ++k)
      *reinterpret_cast<float4*>(&Ca[4*k]) = *reinterpret_cast<const float4*>(r + DINNER + DSTATE + 4*k);
    aA = dap[0];
  }
  for (int t = 0; t < CHUNK; t += 2){
    {
      const float* r = base + (size_t)(t+1)*CONVDIM;
      ylB = r[xoff];
      #pragma unroll
      for (int k = 0; k < 4; ++k)
        *reinterpret_cast<float4*>(&Cb[4*k]) = *reinterpret_cast<const float4*>(r + DINNER + DSTATE + 4*k);
      aB = dap[(size_t)(t+1)*NHEADS];
      cum *= aA;
      float corr = 0.f;
      #pragma unroll
      for (int n = 0; n < 16; ++n) corr = fmaf(hi[n], Ca[n], corr);
      yp[(size_t)t*DINNER] = f2bfu(ylA + cum*corr);
    }
    {
      const float* r = base + (size_t)(t+2)*CONVDIM;
      ylA = r[xoff];
      #pragma unroll
      for (int k = 0; k < 4; ++k)
        *reinterpret_cast<float4*>(&Ca[4*k]) = *reinterpret_cast<const float4*>(r + DINNER + DSTATE + 4*k);
      aA = dap[(size_t)(t+2)*NHEADS];
      cum *= aB;
      float corr = 0.f;
      #pragma unroll
      for (int n = 0; n < 16; ++n) corr = fmaf(hi[n], Cb[n], corr);
      yp[(size_t)(t+1)*DINNER] = f2bfu(ylB + cum*corr);
    }
  }
}

// ---------------- gate (silu(z)*y) + RMSNorm + cast bf16 (in-place over z) ----------------
__global__ __launch_bounds__(64) void k_gate(const unsigned short* __restrict__ ybf,
                                             unsigned short* __restrict__ zbf,
                                             const float* __restrict__ nw){
  int row = blockIdx.x; int l = threadIdx.x;
  size_t base = (size_t)row*DINNER + l*8;
  ushort8 yv = *reinterpret_cast<const ushort8*>(ybf + base);
  ushort8 zv = *reinterpret_cast<const ushort8*>(zbf + base);
  float tv[8]; float ss = 0.f;
  #pragma unroll
  for (int j = 0; j < 8; ++j){
    float yf = bfu2f(yv[j]);
    float zf = bfu2f(zv[j]);
    float s = zf / (1.f + __expf(-zf));
    float t = yf * s; tv[j] = t; ss += t*t;
  }
  #pragma unroll
  for (int m = 1; m <= 32; m <<= 1) ss += __shfl_xor(ss, m, 64);
  float scale = rsqrtf(ss * (1.f/DINNER) + 1e-5f);
  ushort8 o;
  #pragma unroll
  for (int j = 0; j < 8; ++j) o[j] = f2bfu(tv[j] * scale * nw[l*8+j]);
  *reinterpret_cast<ushort8*>(zbf + base) = o;
}

extern "C" void kernel_launch(void* const* d_in, const int* in_sizes, int n_in,
                              void* d_out, int out_size, void* d_ws, size_t ws_size,
                              hipStream_t stream)
{
  const float* u       = (const float*)d_in[0];
  const float* W_in    = (const float*)d_in[1];
  const float* conv_w  = (const float*)d_in[2];
  const float* conv_b  = (const float*)d_in[3];
  const float* dt_bias = (const float*)d_in[4];
  const float* A_log   = (const float*)d_in[5];
  const float* Dvec    = (const float*)d_in[6];
  const float* norm_w  = (const float*)d_in[7];
  const float* W_out   = (const float*)d_in[8];
  float* out = (float*)d_out;
  char* ws = (char*)d_ws;

  unsigned short* ubf   = (unsigned short*)(ws + 0);          // 16,777,216 B (dead after GEMM1)
  float* chst           = (float*)(ws + 0);                   // 16,777,216 B (scan passes, overlaps ubf)
  unsigned short* wintT = (unsigned short*)(ws + 16777216);   //    557,056 B
  unsigned short* woutT = (unsigned short*)(ws + 17334272);   //    262,144 B
  unsigned short* zbf   = (unsigned short*)(ws + 17596416);   // 33,554,432 B (becomes t after gate)
  unsigned short* xbcbf = (unsigned short*)(ws + 51150848);   // 35,651,584 B (reused as y bf16)
  float* dtraw          = (float*)(ws + 86802432);            //  4,194,304 B (Pp overlaps after k_dtda)
  float* Pp             = dtraw;                              //     65,536 B
  float* convo          = (float*)(ws + 90996736);            // 71,303,168 B (x-slot becomes y_local)
  float* dtq            = (float*)(ws + 162299904);           //  4,194,304 B
  float* daq            = (float*)(ws + 166494208);           //  4,194,304 B  (total 170,688,512 B)
  unsigned short* ybf   = xbcbf;

  k_cast_u<<<NROWS*DMODEL/1024, 256, 0, stream>>>(u, ubf);
  k_transpose_cast<<<(DINPROJ*DMODEL+255)/256, 256, 0, stream>>>(W_in, wintT, DMODEL, DINPROJ);
  k_transpose_cast<<<(DINNER*DMODEL+255)/256, 256, 0, stream>>>(W_out, woutT, DINNER, DMODEL);

  dim3 g1(NROWS/128, DINPROJ/64);
  k_gemm<1><<<g1, 256, 0, stream>>>(ubf, wintT, NROWS, DINPROJ, DMODEL, zbf, xbcbf, dtraw, nullptr);

  k_conv<<<NROWS, 256, 0, stream>>>(xbcbf, conv_w, conv_b, convo);
  k_dtda<<<NROWS*NHEADS/256, 256, 0, stream>>>(dtraw, dt_bias, A_log, dtq, daq);

  k_scan1<<<BATCH*2*NCH, 256, 0, stream>>>(convo, dtq, daq, Dvec, chst, Pp);
  k_scan2<<<BATCH*NHEADS, 64, 0, stream>>>(chst, Pp);
  k_scan3<<<BATCH*2*NCH, 256, 0, stream>>>(convo, daq, chst, ybf);

  k_gate<<<NROWS, 64, 0, stream>>>(ybf, zbf, norm_w);

  dim3 g2(NROWS/128, DMODEL/64);
  k_gemm<2><<<g2, 256, 0, stream>>>(zbf, woutT, NROWS, DMODEL, DINNER, nullptr, nullptr, nullptr, out);
}

// Round 5
// 180.296 us; speedup vs baseline: 10.6553x; 1.6042x over previous
//
#include <hip/hip_runtime.h>
#include <hip/hip_bf16.h>
#include <math.h>

#define BATCH   8
#define SEQLEN  4096
#define DMODEL  256
#define DSTATE  16
#define NHEADS  32
#define HEADDIM 16
#define DINNER  512
#define CONVDIM 544
#define DINPROJ 1088
#define NROWS   (BATCH*SEQLEN)
#define CHUNK   64
#define NCH     (SEQLEN/CHUNK)   // 64

typedef __attribute__((ext_vector_type(8))) short short8;
typedef __attribute__((ext_vector_type(8))) unsigned short ushort8;
typedef __attribute__((ext_vector_type(4))) float f32x4;

__device__ __forceinline__ float bfu2f(unsigned short u){
  union { float f; unsigned int i; } x; x.i = ((unsigned int)u) << 16; return x.f;
}
__device__ __forceinline__ unsigned short f2bfu(float f){
  union { float f; unsigned int u; } v; v.f = f;
  v.u += 0x7fffu + ((v.u >> 16) & 1u);
  return (unsigned short)(v.u >> 16);
}

// ---------------- prep: cast u to bf16 ----------------
__global__ __launch_bounds__(256) void k_cast_u(const float* __restrict__ u, unsigned short* __restrict__ ub){
  int i = blockIdx.x*256 + threadIdx.x;
  float4 v = reinterpret_cast<const float4*>(u)[i];
  ushort4 o; o.x=f2bfu(v.x); o.y=f2bfu(v.y); o.z=f2bfu(v.z); o.w=f2bfu(v.w);
  reinterpret_cast<ushort4*>(ub)[i] = o;
}

// ---------------- prep: transpose+cast W (KxN -> NxK bf16) ----------------
__global__ __launch_bounds__(256) void k_transpose_cast(const float* __restrict__ W, unsigned short* __restrict__ WT, int K, int N){
  int idx = blockIdx.x*256 + threadIdx.x;
  if (idx >= N*K) return;
  int n = idx / K, k = idx - n*K;
  WT[idx] = f2bfu(W[(size_t)k*N + n]);
}

// ---------------- bf16 MFMA GEMM: C = A(MxK) * BT(NxK)^T ----------------
template<int EPI>
__global__ __launch_bounds__(256) void k_gemm(
    const unsigned short* __restrict__ A,
    const unsigned short* __restrict__ BT,
    int M, int N, int K,
    unsigned short* __restrict__ oz,
    unsigned short* __restrict__ oxbc,
    float* __restrict__ odtraw,
    float* __restrict__ of32)
{
  __shared__ uint4 lds[768];
  const int tid = threadIdx.x;
  const int lane = tid & 63;
  const int wid = tid >> 6;
  const int wr = wid >> 1, wc = wid & 1;
  const int bm0 = blockIdx.x * 128;
  const int bn0 = blockIdx.y * 64;
  const int fr = lane & 15, kq = lane >> 4;
  f32x4 acc[4][2] = {};
  const int nK = K >> 5;
  for (int kt = 0; kt < nK; ++kt){
    const int k0 = kt << 5;
    #pragma unroll
    for (int i = 0; i < 2; ++i){
      int c = tid + i*256;
      int row = c >> 2, slot = c & 3;
      uint4 v = *reinterpret_cast<const uint4*>(A + (size_t)(bm0+row)*K + k0 + slot*8);
      lds[row*4 + (slot ^ (row & 3))] = v;
    }
    {
      int row = tid >> 2, slot = tid & 3;
      uint4 v = *reinterpret_cast<const uint4*>(BT + (size_t)(bn0+row)*K + k0 + slot*8);
      lds[512 + row*4 + (slot ^ (row & 3))] = v;
    }
    __syncthreads();
    short8 bfrag[2];
    #pragma unroll
    for (int nf = 0; nf < 2; ++nf){
      int rb = wc*32 + nf*16 + fr;
      bfrag[nf] = *reinterpret_cast<const short8*>(&lds[512 + rb*4 + (kq ^ (rb & 3))]);
    }
    #pragma unroll
    for (int mf = 0; mf < 4; ++mf){
      int ra = wr*64 + mf*16 + fr;
      short8 afrag = *reinterpret_cast<const short8*>(&lds[ra*4 + (kq ^ (ra & 3))]);
      #pragma unroll
      for (int nf = 0; nf < 2; ++nf)
        acc[mf][nf] = __builtin_amdgcn_mfma_f32_16x16x32_bf16(afrag, bfrag[nf], acc[mf][nf], 0, 0, 0);
    }
    __syncthreads();
  }
  #pragma unroll
  for (int mf = 0; mf < 4; ++mf){
    #pragma unroll
    for (int nf = 0; nf < 2; ++nf){
      #pragma unroll
      for (int r = 0; r < 4; ++r){
        int m = bm0 + wr*64 + mf*16 + kq*4 + r;
        int n = bn0 + wc*32 + nf*16 + fr;
        float v = acc[mf][nf][r];
        if (EPI == 1){
          if (n < DINNER)                 oz[(size_t)m*DINNER + n] = f2bfu(v);
          else if (n < DINNER + CONVDIM)  oxbc[(size_t)m*CONVDIM + (n - DINNER)] = f2bfu(v);
          else                            odtraw[(size_t)m*NHEADS + (n - DINNER - CONVDIM)] = v;
        } else {
          of32[(size_t)m*N + n] = v;
        }
      }
    }
  }
}

// ---------------- conv+silu for B/C channels only (c=512..543) -> f32 [NROWS][32] ----------------
__global__ __launch_bounds__(256) void k_convbc(const unsigned short* __restrict__ xbc,
                                                const float* __restrict__ cw,
                                                const float* __restrict__ cb,
                                                float* __restrict__ bco){
  const int tid = threadIdx.x;
  const int j = tid & 31;                 // channel - 512
  const int rt = tid >> 5;                // 0..7
  const int r0 = blockIdx.x*64 + rt*8;    // 8 rows per thread
  const int ch = 512 + j;
  const int tloc = r0 & (SEQLEN-1);
  float wv0 = cw[ch*4+0], wv1 = cw[ch*4+1], wv2 = cw[ch*4+2], wv3 = cw[ch*4+3];
  const float bias = cb[ch];
  float xr[11];
  #pragma unroll
  for (int k = 0; k < 11; ++k){
    int r = r0 - 3 + k;
    xr[k] = (tloc - 3 + k < 0) ? 0.f : bfu2f(xbc[(size_t)r*CONVDIM + ch]);
  }
  #pragma unroll
  for (int i = 0; i < 8; ++i){
    float acc = fmaf(wv0, xr[i], fmaf(wv1, xr[i+1], fmaf(wv2, xr[i+2], fmaf(wv3, xr[i+3], bias))));
    bco[(size_t)(r0+i)*32 + j] = acc / (1.f + __expf(-acc));
  }
}

// ---------------- dt = softplus(dtraw + bias); dA = exp(-exp(A_log)*dt) ----------------
__global__ __launch_bounds__(256) void k_dtda(const float* __restrict__ dtraw,
                                              const float* __restrict__ dt_bias,
                                              const float* __restrict__ A_log,
                                              float* __restrict__ dt_o,
                                              float* __restrict__ dA_o){
  int i = blockIdx.x*256 + threadIdx.x;   // NROWS*NHEADS
  int h = i & (NHEADS-1);
  float x = dtraw[i] + dt_bias[h];
  float dt = (x > 20.f) ? x : log1pf(expf(x));
  dt_o[i] = dt;
  dA_o[i] = expf(-expf(A_log[h]) * dt);
}

// ======== chunked selective scan, 4 heads/wave, full-n per lane ========
// Fuses the x-channel depthwise conv+SiLU (sliding register window over raw
// bf16 xbc). B/C (post-conv, from convbc) + dt/da staged in LDS per chunk.
// pass 1: local scan (h0=0) -> y_local f32 [NROWS][512]; chunk state -> st; decay prod -> Pp.
__global__ __launch_bounds__(256,4) void k_scan1(
    const unsigned short* __restrict__ xbc, const float* __restrict__ bc,
    const float* __restrict__ dta, const float* __restrict__ daa,
    const float* __restrict__ cwv, const float* __restrict__ cbv,
    const float* __restrict__ Dv,
    float* __restrict__ yl, float* __restrict__ st, float* __restrict__ Pp)
{
  __shared__ float sBC[65*32];
  __shared__ float sdt[65*16];
  __shared__ float sda[65*16];
  const int tid = threadIdx.x;
  const int bid = blockIdx.x;
  const int qh = bid & 1;
  const int c  = (bid >> 1) & (NCH-1);
  const int b  = bid >> 7;
  const int w  = tid >> 6;
  const int l  = tid & 63;
  const int q  = qh*4 + w;
  const int hh = l >> 4, p = l & 15;
  const int h  = q*4 + hh;
  const size_t row0 = (size_t)b*SEQLEN + (size_t)c*CHUNK;
  const int xoff = q*64 + l;
  // stage B/C rows (contiguous 8KB)
  {
    const float* src = bc + row0*32;
    #pragma unroll
    for (int i = 0; i < 2; ++i){
      int idx = tid + i*256;
      *reinterpret_cast<float4*>(&sBC[idx*4]) = *reinterpret_cast<const float4*>(src + (size_t)idx*4);
    }
  }
  // stage dt/da [64][16] slice for this block's 16 heads
  {
    int t = tid >> 2, g = (tid & 3)*4;
    *reinterpret_cast<float4*>(&sdt[t*16+g]) =
      *reinterpret_cast<const float4*>(dta + (row0+t)*NHEADS + qh*16 + g);
    *reinterpret_cast<float4*>(&sda[t*16+g]) =
      *reinterpret_cast<const float4*>(daa + (row0+t)*NHEADS + qh*16 + g);
  }
  const float cw0 = cwv[xoff*4+0], cw1 = cwv[xoff*4+1], cw2 = cwv[xoff*4+2], cw3 = cwv[xoff*4+3];
  const float cb0 = cbv[xoff];
  const float Dh = Dv[h];
  const int dIdx = w*4 + hh;
  // conv window: wA=x_{t-3}, wB=x_{t-2}, wC=x_{t-1}
  float wA, wB, wC;
  if (c == 0){ wA = wB = wC = 0.f; }
  else {
    wA = bfu2f(xbc[(row0-3)*CONVDIM + xoff]);
    wB = bfu2f(xbc[(row0-2)*CONVDIM + xoff]);
    wC = bfu2f(xbc[(row0-1)*CONVDIM + xoff]);
  }
  float xq0 = bfu2f(xbc[(row0+0)*CONVDIM + xoff]);
  float xq1 = bfu2f(xbc[(row0+1)*CONVDIM + xoff]);
  float xq2 = bfu2f(xbc[(row0+2)*CONVDIM + xoff]);
  float xq3 = bfu2f(xbc[(row0+3)*CONVDIM + xoff]);
  __syncthreads();
  float BA[32], BB[32];
  #pragma unroll
  for (int k = 0; k < 8; ++k)
    *reinterpret_cast<float4*>(&BA[4*k]) = *reinterpret_cast<const float4*>(&sBC[4*k]);
  float dtA = sdt[dIdx], daA = sda[dIdx];
  float dtB, daB;
  float hs[16];
  #pragma unroll
  for (int n = 0; n < 16; ++n) hs[n] = 0.f;
  float cum = 1.f;

#define S1STEP(CUR, NXT, DTC, DAC, DTN, DAN, XQ, T) {                          \
    const int t_ = (T);                                                        \
    _Pragma("unroll")                                                          \
    for (int k = 0; k < 8; ++k)                                                \
      *reinterpret_cast<float4*>(&NXT[4*k]) =                                  \
        *reinterpret_cast<const float4*>(&sBC[(t_+1)*32 + 4*k]);               \
    DTN = sdt[(t_+1)*16 + dIdx]; DAN = sda[(t_+1)*16 + dIdx];                  \
    float xnew = bfu2f(xbc[(row0 + t_ + 4)*CONVDIM + xoff]);                   \
    float xc = fmaf(cw0, wA, fmaf(cw1, wB, fmaf(cw2, wC, fmaf(cw3, XQ, cb0))));\
    wA = wB; wB = wC; wC = XQ; XQ = xnew;                                      \
    float xs = xc / (1.f + __expf(-xc));                                       \
    float dx = DTC * xs;                                                       \
    float y_ = 0.f;                                                            \
    _Pragma("unroll")                                                          \
    for (int n = 0; n < 16; ++n) hs[n] = fmaf(DAC, hs[n], dx*CUR[n]);          \
    _Pragma("unroll")                                                          \
    for (int n = 0; n < 16; ++n) y_ = fmaf(hs[n], CUR[16+n], y_);              \
    cum *= DAC;                                                                \
    yl[(row0 + t_)*DINNER + xoff] = y_ + Dh*xs;                                \
  }

  for (int T = 0; T < CHUNK; T += 4){
    S1STEP(BA, BB, dtA, daA, dtB, daB, xq0, T+0);
    S1STEP(BB, BA, dtB, daB, dtA, daA, xq1, T+1);
    S1STEP(BA, BB, dtA, daA, dtB, daB, xq2, T+2);
    S1STEP(BB, BA, dtB, daB, dtA, daA, xq3, T+3);
  }
#undef S1STEP
  float* sp = st + (((size_t)(b*NHEADS + h)*NCH + c)*16 + p)*16;
  #pragma unroll
  for (int k = 0; k < 4; ++k)
    *reinterpret_cast<float4*>(sp + 4*k) = make_float4(hs[4*k], hs[4*k+1], hs[4*k+2], hs[4*k+3]);
  if (p == 0) Pp[((size_t)b*NHEADS + h)*NCH + c] = cum;
}

// pass 2: inter-chunk scan; st[c] := hinit_c in place.
__global__ __launch_bounds__(64) void k_scan2(float* __restrict__ st, const float* __restrict__ Pp){
  const int bh = blockIdx.x;
  const int l = threadIdx.x;
  float* sb = st + (size_t)bh*NCH*256 + l*4;
  const float* pb = Pp + (size_t)bh*NCH;
  float4 carry = make_float4(0.f,0.f,0.f,0.f);
  float4 Hb[4]; float Pb[4];
  #pragma unroll
  for (int i = 0; i < 4; ++i){
    Hb[i] = *reinterpret_cast<const float4*>(sb + (size_t)i*256);
    Pb[i] = pb[i];
  }
  for (int c0 = 0; c0 < NCH; c0 += 4){
    #pragma unroll
    for (int i = 0; i < 4; ++i){
      const int cc = c0 + i;
      float4 Hc = Hb[i]; float Pc = Pb[i];
      if (cc + 4 < NCH){
        Hb[i] = *reinterpret_cast<const float4*>(sb + (size_t)(cc+4)*256);
        Pb[i] = pb[cc+4];
      }
      *reinterpret_cast<float4*>(sb + (size_t)cc*256) = carry;
      carry.x = fmaf(Pc, carry.x, Hc.x);
      carry.y = fmaf(Pc, carry.y, Hc.y);
      carry.z = fmaf(Pc, carry.z, Hc.z);
      carry.w = fmaf(Pc, carry.w, Hc.w);
    }
  }
}

// pass 3: y_t = y_local_t + cum_t * (hinit . C_t) -> bf16
__global__ __launch_bounds__(256,4) void k_scan3(
    const float* __restrict__ yl, const float* __restrict__ bc,
    const float* __restrict__ daa, const float* __restrict__ st,
    unsigned short* __restrict__ ybf)
{
  __shared__ float sC[65*16];
  __shared__ float sda[65*16];
  const int tid = threadIdx.x;
  const int bid = blockIdx.x;
  const int qh = bid & 1;
  const int c  = (bid >> 1) & (NCH-1);
  const int b  = bid >> 7;
  const int w  = tid >> 6;
  const int l  = tid & 63;
  const int q  = qh*4 + w;
  const int hh = l >> 4, p = l & 15;
  const int h  = q*4 + hh;
  const size_t row0 = (size_t)b*SEQLEN + (size_t)c*CHUNK;
  const int xoff = q*64 + l;
  {
    int t = tid >> 2, g = (tid & 3)*4;
    *reinterpret_cast<float4*>(&sC[t*16+g]) =
      *reinterpret_cast<const float4*>(bc + (row0+t)*32 + 16 + g);
    *reinterpret_cast<float4*>(&sda[t*16+g]) =
      *reinterpret_cast<const float4*>(daa + (row0+t)*NHEADS + qh*16 + g);
  }
  float hi[16];
  {
    const float* sp = st + (((size_t)(b*NHEADS + h)*NCH + c)*16 + p)*16;
    #pragma unroll
    for (int k = 0; k < 4; ++k){
      float4 v = *reinterpret_cast<const float4*>(sp + 4*k);
      hi[4*k] = v.x; hi[4*k+1] = v.y; hi[4*k+2] = v.z; hi[4*k+3] = v.w;
    }
  }
  float yq0 = yl[(row0+0)*DINNER + xoff];
  float yq1 = yl[(row0+1)*DINNER + xoff];
  float yq2 = yl[(row0+2)*DINNER + xoff];
  float yq3 = yl[(row0+3)*DINNER + xoff];
  __syncthreads();
  const int dIdx = w*4 + hh;
  float CA[16], CB[16];
  #pragma unroll
  for (int k = 0; k < 4; ++k)
    *reinterpret_cast<float4*>(&CA[4*k]) = *reinterpret_cast<const float4*>(&sC[4*k]);
  float daA = sda[dIdx], daB;
  float cum = 1.f;

#define S3STEP(CUR, NXT, DAC, DAN, YQ, T) {                                    \
    const int t_ = (T);                                                        \
    _Pragma("unroll")                                                          \
    for (int k = 0; k < 4; ++k)                                                \
      *reinterpret_cast<float4*>(&NXT[4*k]) =                                  \
        *reinterpret_cast<const float4*>(&sC[(t_+1)*16 + 4*k]);                \
    DAN = sda[(t_+1)*16 + dIdx];                                               \
    float ynew = yl[(row0 + t_ + 4)*DINNER + xoff];                            \
    cum *= DAC;                                                                \
    float corr = 0.f;                                                          \
    _Pragma("unroll")                                                          \
    for (int n = 0; n < 16; ++n) corr = fmaf(hi[n], CUR[n], corr);             \
    ybf[(row0 + t_)*DINNER + xoff] = f2bfu(YQ + cum*corr);                     \
    YQ = ynew;                                                                 \
  }

  for (int T = 0; T < CHUNK; T += 4){
    S3STEP(CA, CB, daA, daB, yq0, T+0);
    S3STEP(CB, CA, daB, daA, yq1, T+1);
    S3STEP(CA, CB, daA, daB, yq2, T+2);
    S3STEP(CB, CA, daB, daA, yq3, T+3);
  }
#undef S3STEP
}

// ---------------- gate (silu(z)*y) + RMSNorm + cast bf16 (in-place over z) ----------------
__global__ __launch_bounds__(256) void k_gate(const unsigned short* __restrict__ ybf,
                                              unsigned short* __restrict__ zbf,
                                              const float* __restrict__ nw){
  int row = blockIdx.x*4 + (threadIdx.x >> 6);
  int l = threadIdx.x & 63;
  size_t base = (size_t)row*DINNER + l*8;
  ushort8 yv = *reinterpret_cast<const ushort8*>(ybf + base);
  ushort8 zv = *reinterpret_cast<const ushort8*>(zbf + base);
  float tv[8]; float ss = 0.f;
  #pragma unroll
  for (int j = 0; j < 8; ++j){
    float yf = bfu2f(yv[j]);
    float zf = bfu2f(zv[j]);
    float s = zf / (1.f + __expf(-zf));
    float t = yf * s; tv[j] = t; ss += t*t;
  }
  #pragma unroll
  for (int m = 1; m <= 32; m <<= 1) ss += __shfl_xor(ss, m, 64);
  float scale = rsqrtf(ss * (1.f/DINNER) + 1e-5f);
  ushort8 o;
  #pragma unroll
  for (int j = 0; j < 8; ++j) o[j] = f2bfu(tv[j] * scale * nw[l*8+j]);
  *reinterpret_cast<ushort8*>(zbf + base) = o;
}

extern "C" void kernel_launch(void* const* d_in, const int* in_sizes, int n_in,
                              void* d_out, int out_size, void* d_ws, size_t ws_size,
                              hipStream_t stream)
{
  const float* u       = (const float*)d_in[0];
  const float* W_in    = (const float*)d_in[1];
  const float* conv_w  = (const float*)d_in[2];
  const float* conv_b  = (const float*)d_in[3];
  const float* dt_bias = (const float*)d_in[4];
  const float* A_log   = (const float*)d_in[5];
  const float* Dvec    = (const float*)d_in[6];
  const float* norm_w  = (const float*)d_in[7];
  const float* W_out   = (const float*)d_in[8];
  float* out = (float*)d_out;
  char* ws = (char*)d_ws;

  unsigned short* ubf   = (unsigned short*)(ws + 0);          // 16,777,216 B (dead after GEMM1)
  float* chst           = (float*)(ws + 0);                   // 16,777,216 B (scan, overlaps ubf)
  unsigned short* wintT = (unsigned short*)(ws + 16777216);   //    557,056 B
  unsigned short* woutT = (unsigned short*)(ws + 17334272);   //    262,144 B
  unsigned short* zbf   = (unsigned short*)(ws + 17596416);   // 33,554,432 B (becomes t after gate)
  unsigned short* xbcbf = (unsigned short*)(ws + 51150848);   // 35,651,584 B (reused as y bf16 in scan3)
  float* dtraw          = (float*)(ws + 86802432);            //  4,194,304 B (Pp overlaps after k_dtda)
  float* Pp             = dtraw;                              //     65,536 B
  float* ylocal         = (float*)(ws + 90996736);            // 67,108,864 B
  float* convoBC        = (float*)(ws + 158105600);           //  4,194,304 B
  float* dtq            = (float*)(ws + 162299904);           //  4,194,304 B
  float* daq            = (float*)(ws + 166494208);           //  4,194,304 B  (total 170,688,512 B)
  unsigned short* ybf   = xbcbf;

  k_cast_u<<<NROWS*DMODEL/1024, 256, 0, stream>>>(u, ubf);
  k_transpose_cast<<<(DINPROJ*DMODEL+255)/256, 256, 0, stream>>>(W_in, wintT, DMODEL, DINPROJ);
  k_transpose_cast<<<(DINNER*DMODEL+255)/256, 256, 0, stream>>>(W_out, woutT, DINNER, DMODEL);

  dim3 g1(NROWS/128, DINPROJ/64);
  k_gemm<1><<<g1, 256, 0, stream>>>(ubf, wintT, NROWS, DINPROJ, DMODEL, zbf, xbcbf, dtraw, nullptr);

  k_convbc<<<NROWS/64, 256, 0, stream>>>(xbcbf, conv_w, conv_b, convoBC);
  k_dtda<<<NROWS*NHEADS/256, 256, 0, stream>>>(dtraw, dt_bias, A_log, dtq, daq);

  k_scan1<<<BATCH*2*NCH, 256, 0, stream>>>(xbcbf, convoBC, dtq, daq, conv_w, conv_b, Dvec,
                                           ylocal, chst, Pp);
  k_scan2<<<BATCH*NHEADS, 64, 0, stream>>>(chst, Pp);
  k_scan3<<<BATCH*2*NCH, 256, 0, stream>>>(ylocal, convoBC, daq, chst, ybf);

  k_gate<<<NROWS/4, 256, 0, stream>>>(ybf, zbf, norm_w);

  dim3 g2(NROWS/128, DMODEL/64);
  k_gemm<2><<<g2, 256, 0, stream>>>(zbf, woutT, NROWS, DMODEL, DINNER, nullptr, nullptr, nullptr, out);
}

// Round 6
// 177.007 us; speedup vs baseline: 10.8533x; 1.0186x over previous
//
#include <hip/hip_runtime.h>
#include <hip/hip_bf16.h>
#include <math.h>

#define BATCH   8
#define SEQLEN  4096
#define DMODEL  256
#define DSTATE  16
#define NHEADS  32
#define HEADDIM 16
#define DINNER  512
#define CONVDIM 544
#define DINPROJ 1088
#define NROWS   (BATCH*SEQLEN)
#define CHUNK   64
#define NCH     (SEQLEN/CHUNK)   // 64

typedef __attribute__((ext_vector_type(8))) short short8;
typedef __attribute__((ext_vector_type(8))) unsigned short ushort8;
typedef __attribute__((ext_vector_type(4))) float f32x4;

#define LDSP(x) ((__attribute__((address_space(3))) void*)(x))
#define GLBP(x) ((const __attribute__((address_space(1))) void*)(x))

__device__ __forceinline__ float bfu2f(unsigned short u){
  union { float f; unsigned int i; } x; x.i = ((unsigned int)u) << 16; return x.f;
}
__device__ __forceinline__ unsigned short f2bfu(float f){
  union { float f; unsigned int u; } v; v.f = f;
  v.u += 0x7fffu + ((v.u >> 16) & 1u);
  return (unsigned short)(v.u >> 16);
}

// ---------------- prep: cast u to bf16 ----------------
__global__ __launch_bounds__(256) void k_cast_u(const float* __restrict__ u, unsigned short* __restrict__ ub){
  int i = blockIdx.x*256 + threadIdx.x;
  float4 v = reinterpret_cast<const float4*>(u)[i];
  ushort4 o; o.x=f2bfu(v.x); o.y=f2bfu(v.y); o.z=f2bfu(v.z); o.w=f2bfu(v.w);
  reinterpret_cast<ushort4*>(ub)[i] = o;
}

// ---------------- prep: transpose+cast W (KxN -> NxK bf16) ----------------
__global__ __launch_bounds__(256) void k_transpose_cast(const float* __restrict__ W, unsigned short* __restrict__ WT, int K, int N){
  int idx = blockIdx.x*256 + threadIdx.x;
  if (idx >= N*K) return;
  int n = idx / K, k = idx - n*K;
  WT[idx] = f2bfu(W[(size_t)k*N + n]);
}

// ---------------- bf16 MFMA GEMM: C = A(MxK) * BT(NxK)^T ----------------
// BM=128, BN template (128 or 64), BK=32. 4 waves (2x2). 2-phase pipeline:
// global_load_lds (16B) double-buffered, pre-swizzled global source so the
// linear LDS dest acts as an XOR-swizzled tile (conflict-free ds_read_b128).
template<int EPI, int BN>
__global__ __launch_bounds__(256) void k_gemm(
    const unsigned short* __restrict__ A,
    const unsigned short* __restrict__ BT,
    int K, int nbase,
    unsigned short* __restrict__ oz,
    unsigned short* __restrict__ oxbc,
    float* __restrict__ odtraw,
    float* __restrict__ of32, int Nout)
{
  constexpr int ABYTES = 128*64;        // A tile: 128 rows x 32 bf16
  constexpr int BBYTES = BN*64;
  constexpr int BUFB   = ABYTES + BBYTES;
  constexpr int NF     = BN/32;         // N-frags per wave (128->4, 64->2)
  constexpr int BCALLS = BBYTES/4096;   // gload_lds calls per wave for B
  __shared__ __align__(16) unsigned char lds[2*BUFB];
  const int tid = threadIdx.x;
  const int l   = tid & 63;
  const int w   = tid >> 6;
  const int wr  = w >> 1, wc = w & 1;
  const int bm0 = blockIdx.x * 128;
  const int bn0 = nbase + blockIdx.y * BN;
  const int fr  = l & 15, kq = l >> 4;
  f32x4 acc[4][NF] = {};

  auto STAGE = [&](int buf, int kt){
    const int k0 = kt << 5;
    unsigned char* lb = (unsigned char*)lds + buf*BUFB;
    #pragma unroll
    for (int i = 0; i < 2; ++i){
      int row = w*32 + i*16 + (l>>2);
      int sl  = (l&3) ^ ((row>>1)&3);
      const unsigned short* gp = A + (size_t)(bm0+row)*K + k0 + sl*8;
      __builtin_amdgcn_global_load_lds(GLBP(gp), LDSP(lb + w*2048 + i*1024), 16, 0, 0);
    }
    #pragma unroll
    for (int i = 0; i < BCALLS; ++i){
      int row = w*(BCALLS*16) + i*16 + (l>>2);
      int sl  = (l&3) ^ ((row>>1)&3);
      const unsigned short* gp = BT + (size_t)(bn0+row)*K + k0 + sl*8;
      __builtin_amdgcn_global_load_lds(GLBP(gp), LDSP(lb + ABYTES + w*(BCALLS*1024) + i*1024), 16, 0, 0);
    }
  };

  const int nK = K >> 5;
  STAGE(0, 0);
  __syncthreads();
  int cur = 0;
  for (int kt = 0; kt < nK; ++kt){
    if (kt + 1 < nK) STAGE(cur^1, kt+1);
    const unsigned char* ab = (const unsigned char*)lds + cur*BUFB;
    const unsigned char* bb = ab + ABYTES;
    short8 bf[NF];
    #pragma unroll
    for (int nf = 0; nf < NF; ++nf){
      int rb = wc*(BN/2) + nf*16 + fr;
      bf[nf] = *reinterpret_cast<const short8*>(bb + rb*64 + ((kq ^ ((rb>>1)&3))*16));
    }
    #pragma unroll
    for (int mf = 0; mf < 4; ++mf){
      int ra = wr*64 + mf*16 + fr;
      short8 af = *reinterpret_cast<const short8*>(ab + ra*64 + ((kq ^ ((ra>>1)&3))*16));
      #pragma unroll
      for (int nf = 0; nf < NF; ++nf)
        acc[mf][nf] = __builtin_amdgcn_mfma_f32_16x16x32_bf16(af, bf[nf], acc[mf][nf], 0, 0, 0);
    }
    __syncthreads();
    cur ^= 1;
  }
  #pragma unroll
  for (int mf = 0; mf < 4; ++mf){
    #pragma unroll
    for (int nf = 0; nf < NF; ++nf){
      #pragma unroll
      for (int r = 0; r < 4; ++r){
        int m = bm0 + wr*64 + mf*16 + kq*4 + r;
        int n = bn0 + wc*(BN/2) + nf*16 + fr;
        float v = acc[mf][nf][r];
        if (EPI == 1){
          if (n < DINNER)                 oz[(size_t)m*DINNER + n] = f2bfu(v);
          else if (n < DINNER + CONVDIM)  oxbc[(size_t)m*CONVDIM + (n - DINNER)] = f2bfu(v);
          else                            odtraw[(size_t)m*NHEADS + (n - DINNER - CONVDIM)] = v;
        } else {
          of32[(size_t)m*Nout + n] = v;
        }
      }
    }
  }
}

// ---------------- conv+silu for B/C channels only (c=512..543) -> f32 [NROWS][32] ----------------
__global__ __launch_bounds__(256) void k_convbc(const unsigned short* __restrict__ xbc,
                                                const float* __restrict__ cw,
                                                const float* __restrict__ cb,
                                                float* __restrict__ bco){
  const int tid = threadIdx.x;
  const int j = tid & 31;
  const int rt = tid >> 5;
  const int r0 = blockIdx.x*64 + rt*8;
  const int ch = 512 + j;
  const int tloc = r0 & (SEQLEN-1);
  float wv0 = cw[ch*4+0], wv1 = cw[ch*4+1], wv2 = cw[ch*4+2], wv3 = cw[ch*4+3];
  const float bias = cb[ch];
  float xr[11];
  #pragma unroll
  for (int k = 0; k < 11; ++k){
    int r = r0 - 3 + k;
    xr[k] = (tloc - 3 + k < 0) ? 0.f : bfu2f(xbc[(size_t)r*CONVDIM + ch]);
  }
  #pragma unroll
  for (int i = 0; i < 8; ++i){
    float acc = fmaf(wv0, xr[i], fmaf(wv1, xr[i+1], fmaf(wv2, xr[i+2], fmaf(wv3, xr[i+3], bias))));
    bco[(size_t)(r0+i)*32 + j] = acc / (1.f + __expf(-acc));
  }
}

// ---------------- dt = softplus(dtraw + bias); dA = exp(-exp(A_log)*dt) ----------------
__global__ __launch_bounds__(256) void k_dtda(const float* __restrict__ dtraw,
                                              const float* __restrict__ dt_bias,
                                              const float* __restrict__ A_log,
                                              float* __restrict__ dt_o,
                                              float* __restrict__ dA_o){
  int i = blockIdx.x*256 + threadIdx.x;   // NROWS*NHEADS
  int h = i & (NHEADS-1);
  float x = dtraw[i] + dt_bias[h];
  float dt = (x > 20.f) ? x : log1pf(expf(x));
  dt_o[i] = dt;
  dA_o[i] = expf(-expf(A_log[h]) * dt);
}

// ======== chunked selective scan, 4 heads/wave, full-n per lane ========
__global__ __launch_bounds__(256,4) void k_scan1(
    const unsigned short* __restrict__ xbc, const float* __restrict__ bc,
    const float* __restrict__ dta, const float* __restrict__ daa,
    const float* __restrict__ cwv, const float* __restrict__ cbv,
    const float* __restrict__ Dv,
    float* __restrict__ yl, float* __restrict__ st, float* __restrict__ Pp)
{
  __shared__ float sBC[65*32];
  __shared__ float sdt[65*16];
  __shared__ float sda[65*16];
  const int tid = threadIdx.x;
  const int bid = blockIdx.x;
  const int qh = bid & 1;
  const int c  = (bid >> 1) & (NCH-1);
  const int b  = bid >> 7;
  const int w  = tid >> 6;
  const int l  = tid & 63;
  const int q  = qh*4 + w;
  const int hh = l >> 4, p = l & 15;
  const int h  = q*4 + hh;
  const size_t row0 = (size_t)b*SEQLEN + (size_t)c*CHUNK;
  const int xoff = q*64 + l;
  {
    const float* src = bc + row0*32;
    #pragma unroll
    for (int i = 0; i < 2; ++i){
      int idx = tid + i*256;
      *reinterpret_cast<float4*>(&sBC[idx*4]) = *reinterpret_cast<const float4*>(src + (size_t)idx*4);
    }
  }
  {
    int t = tid >> 2, g = (tid & 3)*4;
    *reinterpret_cast<float4*>(&sdt[t*16+g]) =
      *reinterpret_cast<const float4*>(dta + (row0+t)*NHEADS + qh*16 + g);
    *reinterpret_cast<float4*>(&sda[t*16+g]) =
      *reinterpret_cast<const float4*>(daa + (row0+t)*NHEADS + qh*16 + g);
  }
  const float cw0 = cwv[xoff*4+0], cw1 = cwv[xoff*4+1], cw2 = cwv[xoff*4+2], cw3 = cwv[xoff*4+3];
  const float cb0 = cbv[xoff];
  const float Dh = Dv[h];
  const int dIdx = w*4 + hh;
  float wA, wB, wC;
  if (c == 0){ wA = wB = wC = 0.f; }
  else {
    wA = bfu2f(xbc[(row0-3)*CONVDIM + xoff]);
    wB = bfu2f(xbc[(row0-2)*CONVDIM + xoff]);
    wC = bfu2f(xbc[(row0-1)*CONVDIM + xoff]);
  }
  float xq0 = bfu2f(xbc[(row0+0)*CONVDIM + xoff]);
  float xq1 = bfu2f(xbc[(row0+1)*CONVDIM + xoff]);
  float xq2 = bfu2f(xbc[(row0+2)*CONVDIM + xoff]);
  float xq3 = bfu2f(xbc[(row0+3)*CONVDIM + xoff]);
  __syncthreads();
  float BA[32], BB[32];
  #pragma unroll
  for (int k = 0; k < 8; ++k)
    *reinterpret_cast<float4*>(&BA[4*k]) = *reinterpret_cast<const float4*>(&sBC[4*k]);
  float dtA = sdt[dIdx], daA = sda[dIdx];
  float dtB, daB;
  float hs[16];
  #pragma unroll
  for (int n = 0; n < 16; ++n) hs[n] = 0.f;
  float cum = 1.f;

#define S1STEP(CUR, NXT, DTC, DAC, DTN, DAN, XQ, T) {                          \
    const int t_ = (T);                                                        \
    _Pragma("unroll")                                                          \
    for (int k = 0; k < 8; ++k)                                                \
      *reinterpret_cast<float4*>(&NXT[4*k]) =                                  \
        *reinterpret_cast<const float4*>(&sBC[(t_+1)*32 + 4*k]);               \
    DTN = sdt[(t_+1)*16 + dIdx]; DAN = sda[(t_+1)*16 + dIdx];                  \
    float xnew = bfu2f(xbc[(row0 + t_ + 4)*CONVDIM + xoff]);                   \
    float xc = fmaf(cw0, wA, fmaf(cw1, wB, fmaf(cw2, wC, fmaf(cw3, XQ, cb0))));\
    wA = wB; wB = wC; wC = XQ; XQ = xnew;                                      \
    float xs = xc / (1.f + __expf(-xc));                                       \
    float dx = DTC * xs;                                                       \
    float y_ = 0.f;                                                            \
    _Pragma("unroll")                                                          \
    for (int n = 0; n < 16; ++n) hs[n] = fmaf(DAC, hs[n], dx*CUR[n]);          \
    _Pragma("unroll")                                                          \
    for (int n = 0; n < 16; ++n) y_ = fmaf(hs[n], CUR[16+n], y_);              \
    cum *= DAC;                                                                \
    yl[(row0 + t_)*DINNER + xoff] = y_ + Dh*xs;                                \
  }

  for (int T = 0; T < CHUNK; T += 4){
    S1STEP(BA, BB, dtA, daA, dtB, daB, xq0, T+0);
    S1STEP(BB, BA, dtB, daB, dtA, daA, xq1, T+1);
    S1STEP(BA, BB, dtA, daA, dtB, daB, xq2, T+2);
    S1STEP(BB, BA, dtB, daB, dtA, daA, xq3, T+3);
  }
#undef S1STEP
  float* sp = st + (((size_t)(b*NHEADS + h)*NCH + c)*16 + p)*16;
  #pragma unroll
  for (int k = 0; k < 4; ++k)
    *reinterpret_cast<float4*>(sp + 4*k) = make_float4(hs[4*k], hs[4*k+1], hs[4*k+2], hs[4*k+3]);
  if (p == 0) Pp[((size_t)b*NHEADS + h)*NCH + c] = cum;
}

// pass 2: inter-chunk scan; st[c] := hinit_c in place.
__global__ __launch_bounds__(64) void k_scan2(float* __restrict__ st, const float* __restrict__ Pp){
  const int bh = blockIdx.x;
  const int l = threadIdx.x;
  float* sb = st + (size_t)bh*NCH*256 + l*4;
  const float* pb = Pp + (size_t)bh*NCH;
  float4 carry = make_float4(0.f,0.f,0.f,0.f);
  float4 Hb[4]; float Pb[4];
  #pragma unroll
  for (int i = 0; i < 4; ++i){
    Hb[i] = *reinterpret_cast<const float4*>(sb + (size_t)i*256);
    Pb[i] = pb[i];
  }
  for (int c0 = 0; c0 < NCH; c0 += 4){
    #pragma unroll
    for (int i = 0; i < 4; ++i){
      const int cc = c0 + i;
      float4 Hc = Hb[i]; float Pc = Pb[i];
      if (cc + 4 < NCH){
        Hb[i] = *reinterpret_cast<const float4*>(sb + (size_t)(cc+4)*256);
        Pb[i] = pb[cc+4];
      }
      *reinterpret_cast<float4*>(sb + (size_t)cc*256) = carry;
      carry.x = fmaf(Pc, carry.x, Hc.x);
      carry.y = fmaf(Pc, carry.y, Hc.y);
      carry.z = fmaf(Pc, carry.z, Hc.z);
      carry.w = fmaf(Pc, carry.w, Hc.w);
    }
  }
}

// pass 3: y_t = y_local_t + cum_t * (hinit . C_t) -> bf16
__global__ __launch_bounds__(256,4) void k_scan3(
    const float* __restrict__ yl, const float* __restrict__ bc,
    const float* __restrict__ daa, const float* __restrict__ st,
    unsigned short* __restrict__ ybf)
{
  __shared__ float sC[65*16];
  __shared__ float sda[65*16];
  const int tid = threadIdx.x;
  const int bid = blockIdx.x;
  const int qh = bid & 1;
  const int c  = (bid >> 1) & (NCH-1);
  const int b  = bid >> 7;
  const int w  = tid >> 6;
  const int l  = tid & 63;
  const int q  = qh*4 + w;
  const int hh = l >> 4, p = l & 15;
  const int h  = q*4 + hh;
  const size_t row0 = (size_t)b*SEQLEN + (size_t)c*CHUNK;
  const int xoff = q*64 + l;
  {
    int t = tid >> 2, g = (tid & 3)*4;
    *reinterpret_cast<float4*>(&sC[t*16+g]) =
      *reinterpret_cast<const float4*>(bc + (row0+t)*32 + 16 + g);
    *reinterpret_cast<float4*>(&sda[t*16+g]) =
      *reinterpret_cast<const float4*>(daa + (row0+t)*NHEADS + qh*16 + g);
  }
  float hi[16];
  {
    const float* sp = st + (((size_t)(b*NHEADS + h)*NCH + c)*16 + p)*16;
    #pragma unroll
    for (int k = 0; k < 4; ++k){
      float4 v = *reinterpret_cast<const float4*>(sp + 4*k);
      hi[4*k] = v.x; hi[4*k+1] = v.y; hi[4*k+2] = v.z; hi[4*k+3] = v.w;
    }
  }
  float yq0 = yl[(row0+0)*DINNER + xoff];
  float yq1 = yl[(row0+1)*DINNER + xoff];
  float yq2 = yl[(row0+2)*DINNER + xoff];
  float yq3 = yl[(row0+3)*DINNER + xoff];
  __syncthreads();
  const int dIdx = w*4 + hh;
  float CA[16], CB[16];
  #pragma unroll
  for (int k = 0; k < 4; ++k)
    *reinterpret_cast<float4*>(&CA[4*k]) = *reinterpret_cast<const float4*>(&sC[4*k]);
  float daA = sda[dIdx], daB;
  float cum = 1.f;

#define S3STEP(CUR, NXT, DAC, DAN, YQ, T) {                                    \
    const int t_ = (T);                                                        \
    _Pragma("unroll")                                                          \
    for (int k = 0; k < 4; ++k)                                                \
      *reinterpret_cast<float4*>(&NXT[4*k]) =                                  \
        *reinterpret_cast<const float4*>(&sC[(t_+1)*16 + 4*k]);                \
    DAN = sda[(t_+1)*16 + dIdx];                                               \
    float ynew = yl[(row0 + t_ + 4)*DINNER + xoff];                            \
    cum *= DAC;                                                                \
    float corr = 0.f;                                                          \
    _Pragma("unroll")                                                          \
    for (int n = 0; n < 16; ++n) corr = fmaf(hi[n], CUR[n], corr);             \
    ybf[(row0 + t_)*DINNER + xoff] = f2bfu(YQ + cum*corr);                     \
    YQ = ynew;                                                                 \
  }

  for (int T = 0; T < CHUNK; T += 4){
    S3STEP(CA, CB, daA, daB, yq0, T+0);
    S3STEP(CB, CA, daB, daA, yq1, T+1);
    S3STEP(CA, CB, daA, daB, yq2, T+2);
    S3STEP(CB, CA, daB, daA, yq3, T+3);
  }
#undef S3STEP
}

// ---------------- gate (silu(z)*y) + RMSNorm + cast bf16 (in-place over z) ----------------
__global__ __launch_bounds__(256) void k_gate(const unsigned short* __restrict__ ybf,
                                              unsigned short* __restrict__ zbf,
                                              const float* __restrict__ nw){
  int row = blockIdx.x*4 + (threadIdx.x >> 6);
  int l = threadIdx.x & 63;
  size_t base = (size_t)row*DINNER + l*8;
  ushort8 yv = *reinterpret_cast<const ushort8*>(ybf + base);
  ushort8 zv = *reinterpret_cast<const ushort8*>(zbf + base);
  float tv[8]; float ss = 0.f;
  #pragma unroll
  for (int j = 0; j < 8; ++j){
    float yf = bfu2f(yv[j]);
    float zf = bfu2f(zv[j]);
    float s = zf / (1.f + __expf(-zf));
    float t = yf * s; tv[j] = t; ss += t*t;
  }
  #pragma unroll
  for (int m = 1; m <= 32; m <<= 1) ss += __shfl_xor(ss, m, 64);
  float scale = rsqrtf(ss * (1.f/DINNER) + 1e-5f);
  ushort8 o;
  #pragma unroll
  for (int j = 0; j < 8; ++j) o[j] = f2bfu(tv[j] * scale * nw[l*8+j]);
  *reinterpret_cast<ushort8*>(zbf + base) = o;
}

extern "C" void kernel_launch(void* const* d_in, const int* in_sizes, int n_in,
                              void* d_out, int out_size, void* d_ws, size_t ws_size,
                              hipStream_t stream)
{
  const float* u       = (const float*)d_in[0];
  const float* W_in    = (const float*)d_in[1];
  const float* conv_w  = (const float*)d_in[2];
  const float* conv_b  = (const float*)d_in[3];
  const float* dt_bias = (const float*)d_in[4];
  const float* A_log   = (const float*)d_in[5];
  const float* Dvec    = (const float*)d_in[6];
  const float* norm_w  = (const float*)d_in[7];
  const float* W_out   = (const float*)d_in[8];
  float* out = (float*)d_out;
  char* ws = (char*)d_ws;

  unsigned short* ubf   = (unsigned short*)(ws + 0);          // 16,777,216 B (dead after GEMM1)
  float* chst           = (float*)(ws + 0);                   // 16,777,216 B (scan, overlaps ubf)
  unsigned short* wintT = (unsigned short*)(ws + 16777216);   //    557,056 B
  unsigned short* woutT = (unsigned short*)(ws + 17334272);   //    262,144 B
  unsigned short* zbf   = (unsigned short*)(ws + 17596416);   // 33,554,432 B (becomes t after gate)
  unsigned short* xbcbf = (unsigned short*)(ws + 51150848);   // 35,651,584 B (reused as y bf16 in scan3)
  float* dtraw          = (float*)(ws + 86802432);            //  4,194,304 B (Pp overlaps after k_dtda)
  float* Pp             = dtraw;                              //     65,536 B
  float* ylocal         = (float*)(ws + 90996736);            // 67,108,864 B
  float* convoBC        = (float*)(ws + 158105600);           //  4,194,304 B
  float* dtq            = (float*)(ws + 162299904);           //  4,194,304 B
  float* daq            = (float*)(ws + 166494208);           //  4,194,304 B  (total 170,688,512 B)
  unsigned short* ybf   = xbcbf;

  k_cast_u<<<NROWS*DMODEL/1024, 256, 0, stream>>>(u, ubf);
  k_transpose_cast<<<(DINPROJ*DMODEL+255)/256, 256, 0, stream>>>(W_in, wintT, DMODEL, DINPROJ);
  k_transpose_cast<<<(DINNER*DMODEL+255)/256, 256, 0, stream>>>(W_out, woutT, DINNER, DMODEL);

  dim3 g1a(NROWS/128, 1024/128);   // cols 0..1023
  k_gemm<1,128><<<g1a, 256, 0, stream>>>(ubf, wintT, DMODEL, 0, zbf, xbcbf, dtraw, nullptr, 0);
  dim3 g1b(NROWS/128, 1);          // cols 1024..1087
  k_gemm<1,64><<<g1b, 256, 0, stream>>>(ubf, wintT, DMODEL, 1024, zbf, xbcbf, dtraw, nullptr, 0);

  k_convbc<<<NROWS/64, 256, 0, stream>>>(xbcbf, conv_w, conv_b, convoBC);
  k_dtda<<<NROWS*NHEADS/256, 256, 0, stream>>>(dtraw, dt_bias, A_log, dtq, daq);

  k_scan1<<<BATCH*2*NCH, 256, 0, stream>>>(xbcbf, convoBC, dtq, daq, conv_w, conv_b, Dvec,
                                           ylocal, chst, Pp);
  k_scan2<<<BATCH*NHEADS, 64, 0, stream>>>(chst, Pp);
  k_scan3<<<BATCH*2*NCH, 256, 0, stream>>>(ylocal, convoBC, daq, chst, ybf);

  k_gate<<<NROWS/4, 256, 0, stream>>>(ybf, zbf, norm_w);

  dim3 g2(NROWS/128, DMODEL/128);
  k_gemm<2,128><<<g2, 256, 0, stream>>>(zbf, woutT, DINNER, 0, nullptr, nullptr, nullptr, out, DMODEL);
}